// Round 4
// baseline (1178.693 us; speedup 1.0000x reference)
//
#include <hip/hip_runtime.h>
#include <hip/hip_bf16.h>
#include <hip/hip_cooperative_groups.h>

namespace cg = cooperative_groups;

#define BB 64
#define KN 64
#define NPTS 32768
#define DD 2048
#define NCC 2048
#define NH 512
#define MM 4096   /* BB*KN */
#define K2 4096   /* 2*DD  */

typedef unsigned short u16;
typedef unsigned int u32;
typedef __attribute__((ext_vector_type(8))) short short8;
typedef __attribute__((ext_vector_type(4))) float f32x4;

__device__ __forceinline__ float bf2f(u32 u){
  union { u32 i; float f; } v; v.i = u << 16; return v.f;
}
__device__ __forceinline__ u16 f2bf(float f){
  union { float f; u32 i; } v; v.f = f;
  u32 x = v.i;
  return (u16)((x + 0x7fffu + ((x >> 16) & 1u)) >> 16);
}

// global_load_lds: per-lane global src, wave-uniform LDS base (+lane*16 by HW)
typedef __attribute__((address_space(3))) u32 as3_u32;
typedef const __attribute__((address_space(1))) u32 as1_u32;
__device__ __forceinline__ void glds16(const void* g, void* l){
  __builtin_amdgcn_global_load_lds((as1_u32*)g, (as3_u32*)l, 16, 0, 0);
}

struct MegaArgs {
  const int* indexes; const void* feat; const int* labels; const int* knn;
  const void* conv_w; const void* conv_b; const void* w1; const void* b1;
  const void* pa; const void* w2; const void* b2;
  int ff, fcw, fcb, fw1, fb1, fpa, fw2, fb2, fo;
  int* counts; int* cursor; int* used; int* offsets; int* sorted;
  float* norms; float* adj; float* Apart; float* clu;
  u16* xab; u16* cwT; u16* w1T; u16* hb; float* h1; void* out;
};

// ================= mega kernel: whole pipeline, 11 phases, grid=512x256 =================
__global__ __launch_bounds__(256, 2) void k_mega(MegaArgs a){
  __shared__ __align__(16) char smem[33024];
  cg::grid_group grid = cg::this_grid();
  int gid = blockIdx.x, t = threadIdx.x;

  // ---- P0: zero counts/cursor/used + weight transposes ----
  if(gid < 24){
    int idx = gid*256 + t;
    a.counts[idx] = 0;               // counts, cursor, used contiguous (6144 ints)
  }
  for(int u = gid; u < 576; u += 512){
    u16 (*tile)[65] = (u16(*)[65])smem;
    const void* src; u16* dst; int Kd, Nd, isf32, tb;
    if(u < 512){ src=a.conv_w; dst=a.cwT; Kd=K2; Nd=NH; isf32=a.fcw; tb=u; }
    else       { src=a.w1;     dst=a.w1T; Kd=NH; Nd=NH; isf32=a.fw1; tb=u-512; }
    int nbt = Nd >> 6;
    int k0 = (tb / nbt) << 6;
    int n0 = (tb % nbt) << 6;
    if(isf32){
      const float* s = (const float*)src;
      #pragma unroll
      for(int ph=0; ph<16; ph++){
        int idx = ph*256 + t;
        int r = idx >> 6, c = idx & 63;
        tile[r][c] = f2bf(s[(size_t)(k0+r)*Nd + n0 + c]);
      }
    } else {
      const u16* s = (const u16*)src;
      #pragma unroll
      for(int ph=0; ph<16; ph++){
        int idx = ph*256 + t;
        int r = idx >> 6, c = idx & 63;
        tile[r][c] = s[(size_t)(k0+r)*Nd + n0 + c];
      }
    }
    __syncthreads();
    #pragma unroll
    for(int ph=0; ph<16; ph++){
      int idx = ph*256 + t;
      int r = idx >> 6, c = idx & 63;
      dst[(size_t)(n0+r)*Kd + k0 + c] = tile[c][r];
    }
    __syncthreads();
  }
  grid.sync();

  // ---- P1: label count + used-cluster mark ----
  if(gid < 128){
    int n = gid*256 + t;
    atomicAdd(&a.counts[a.labels[n]], 1);
  } else if(gid < 144){
    int idx = (gid-128)*256 + t;          // 4096 knn entries
    a.used[a.labels[a.knn[idx]]] = 1;
  }
  grid.sync();

  // ---- P2: exclusive scan (1 block) ----
  if(gid == 0){
    int* sb = (int*)smem;
    int c[8]; int s = 0;
    #pragma unroll
    for(int i=0;i<8;i++){ c[i] = a.counts[t*8+i]; s += c[i]; }
    sb[t] = s; __syncthreads();
    int v = s;
    for(int off=1; off<256; off<<=1){
      int u = (t>=off) ? sb[t-off] : 0;
      __syncthreads();
      v += u; sb[t] = v;
      __syncthreads();
    }
    int run = v - s;
    #pragma unroll
    for(int i=0;i<8;i++){ a.offsets[t*8+i] = run; run += c[i]; }
  }
  grid.sync();

  // ---- P3: scatter ----
  if(gid < 128){
    int n = gid*256 + t;
    int c = a.labels[n];
    int p = atomicAdd(&a.cursor[c], 1);
    a.sorted[a.offsets[c] + p] = n;
  }
  grid.sync();

  // ---- P4: cluster means (4 clusters/block, x4 row unroll) ----
  {
    int* ridx = (int*)smem;
    for(int c = gid; c < NCC; c += 512){
      if(!a.used[c]) continue;            // block-uniform
      int cnt = a.counts[c], start = a.offsets[c];
      float acc[8] = {0,0,0,0,0,0,0,0};
      for(int base=0; base<cnt; base+=64){
        int take = min(64, cnt-base);
        __syncthreads();
        if(t < take) ridx[t] = a.sorted[start+base+t];
        __syncthreads();
        if(a.ff){
          const float* ff = (const float*)a.feat;
          int r = 0;
          for(; r+4<=take; r+=4){
            const float* p0 = ff + (size_t)ridx[r]*DD + t*8;
            const float* p1 = ff + (size_t)ridx[r+1]*DD + t*8;
            const float* p2 = ff + (size_t)ridx[r+2]*DD + t*8;
            const float* p3 = ff + (size_t)ridx[r+3]*DD + t*8;
            float4 a0=*(const float4*)p0, b0=*(const float4*)(p0+4);
            float4 a1=*(const float4*)p1, b1=*(const float4*)(p1+4);
            float4 a2=*(const float4*)p2, b2=*(const float4*)(p2+4);
            float4 a3=*(const float4*)p3, b3=*(const float4*)(p3+4);
            acc[0]+=a0.x+a1.x+a2.x+a3.x; acc[1]+=a0.y+a1.y+a2.y+a3.y;
            acc[2]+=a0.z+a1.z+a2.z+a3.z; acc[3]+=a0.w+a1.w+a2.w+a3.w;
            acc[4]+=b0.x+b1.x+b2.x+b3.x; acc[5]+=b0.y+b1.y+b2.y+b3.y;
            acc[6]+=b0.z+b1.z+b2.z+b3.z; acc[7]+=b0.w+b1.w+b2.w+b3.w;
          }
          for(; r<take; r++){
            const float* p0 = ff + (size_t)ridx[r]*DD + t*8;
            float4 a0=*(const float4*)p0, b0=*(const float4*)(p0+4);
            acc[0]+=a0.x; acc[1]+=a0.y; acc[2]+=a0.z; acc[3]+=a0.w;
            acc[4]+=b0.x; acc[5]+=b0.y; acc[6]+=b0.z; acc[7]+=b0.w;
          }
        } else {
          const u16* fb = (const u16*)a.feat;
          for(int r=0; r<take; r++){
            const u16* p0 = fb + (size_t)ridx[r]*DD + t*8;
            uint4 v0 = *(const uint4*)p0;
            acc[0]+=bf2f(v0.x&0xffffu); acc[1]+=bf2f(v0.x>>16);
            acc[2]+=bf2f(v0.y&0xffffu); acc[3]+=bf2f(v0.y>>16);
            acc[4]+=bf2f(v0.z&0xffffu); acc[5]+=bf2f(v0.z>>16);
            acc[6]+=bf2f(v0.w&0xffffu); acc[7]+=bf2f(v0.w>>16);
          }
        }
      }
      float div = fmaxf((float)cnt, 1.0f);
      float* o = a.clu + (size_t)c*DD + t*8;
      float4 o0 = make_float4(acc[0]/div, acc[1]/div, acc[2]/div, acc[3]/div);
      float4 o1 = make_float4(acc[4]/div, acc[5]/div, acc[6]/div, acc[7]/div);
      *(float4*)o = o0;
      *(float4*)(o+4) = o1;
      __syncthreads();
    }
  }
  grid.sync();

  // ---- P5: partial A (512 units: b x 8 dgroups) ----
  {
    int b = gid >> 3, g = gid & 7;
    float (*cfT)[68] = (float(*)[68])smem;
    int* sl = (int*)(smem + 17408);
    if(t < 64) sl[t] = a.labels[a.knn[b*64 + t]];
    int qidx = a.indexes[b];
    __syncthreads();
    int i0 = (t & 15)*4, j0 = (t >> 4)*4;
    float acc[4][4];
    #pragma unroll
    for(int x=0;x<4;x++)
      #pragma unroll
      for(int y=0;y<4;y++) acc[x][y] = 0.f;
    for(int ch=g*4; ch<g*4+4; ch++){
      int dbase = ch*64;
      #pragma unroll
      for(int ps=0; ps<16; ps++){
        int idx = ps*256 + t;
        int k = idx >> 6, dd = idx & 63;
        float v;
        if(k == 0){
          size_t fi = (size_t)qidx*DD + dbase + dd;
          v = a.ff ? ((const float*)a.feat)[fi] : bf2f(((const u16*)a.feat)[fi]);
        } else {
          v = a.clu[(size_t)sl[k]*DD + dbase + dd];
        }
        cfT[dd][k] = v;
      }
      __syncthreads();
      #pragma unroll 4
      for(int dd=0; dd<64; dd++){
        float4 av = *(const float4*)&cfT[dd][i0];
        float4 bv = *(const float4*)&cfT[dd][j0];
        float aa[4] = {av.x, av.y, av.z, av.w};
        float bbv[4] = {bv.x, bv.y, bv.z, bv.w};
        #pragma unroll
        for(int ii=0;ii<4;ii++)
          #pragma unroll
          for(int jj=0;jj<4;jj++)
            acc[ii][jj] += aa[ii]*bbv[jj];
      }
      __syncthreads();
    }
    float* op = a.Apart + ((size_t)(g*64 + b))*4096;
    #pragma unroll
    for(int ii=0;ii<4;ii++)
      *(float4*)&op[(i0+ii)*64 + j0] = make_float4(acc[ii][0], acc[ii][1], acc[ii][2], acc[ii][3]);
  }
  grid.sync();

  // ---- P6: final A ----
  if(gid < 64){
    int b = gid;
    float (*A)[65] = (float(*)[65])smem;
    unsigned long long* mb = (unsigned long long*)(smem + 16640);
    int* sl = (int*)(smem + 17152);
    int* sk = (int*)(smem + 17408);
    if(t < 64) sl[t] = a.labels[a.knn[b*64 + t]];
    const float* P = a.Apart + (size_t)b*4096;
    const size_t gs = (size_t)64*4096;
    #pragma unroll
    for(int ps=0; ps<16; ps++){
      int idx = ps*256 + t;
      float s = P[idx] + P[idx+gs] + P[idx+2*gs] + P[idx+3*gs]
              + P[idx+4*gs] + P[idx+5*gs] + P[idx+6*gs] + P[idx+7*gs];
      A[idx>>6][idx&63] = s * 0.2f;
    }
    __syncthreads();
    if(t < 64){
      int dup = 0;
      for(int j=0;j<t;j++) dup |= (sl[j]==sl[t]);
      sk[t] = dup ? 0 : 1;
      unsigned long long chosen = 0;
      const float* row = A[t];
      #pragma unroll
      for(int p=0;p<5;p++){
        float best = -INFINITY; int bi = 0;
        for(int j=0;j<64;j++){
          bool taken = (chosen >> j) & 1ull;
          float v = row[j];
          if(!taken && v > best){ best = v; bi = j; }
        }
        chosen |= (1ull << bi);
      }
      mb[t] = chosen;
      a.norms[b*64+t] = sqrtf(fmaxf(A[t][t]*5.0f, 0.0f));
    }
    __syncthreads();
    float* O = a.adj + (size_t)b*4096;
    #pragma unroll
    for(int ps=0; ps<16; ps++){
      int idx = ps*256 + t;
      int i = idx >> 6, j = idx & 63;
      bool on = ((mb[i]>>j)&1ull) && ((mb[j]>>i)&1ull) && sk[i] && sk[j];
      O[idx] = on ? A[i][j] : 0.0f;
    }
  }
  grid.sync();

  // ---- P7: fused x + agg (256 units); agg reads this thread's own xab writes ----
  if(gid < 256){
    int b = gid >> 2, g = gid & 3;
    float (*adjs)[65] = (float(*)[65])smem;
    float (*nzv)[8]   = (float(*)[8])(smem + 16640);
    u16   (*nzj)[8]   = (u16(*)[8])(smem + 18688);
    int*   nzc        = (int*)(smem + 19712);
    int*   sl         = (int*)(smem + 19968);
    float* sn         = (float*)(smem + 20224);
    const float* Ab = a.adj + (size_t)b*4096;
    #pragma unroll
    for(int ps=0; ps<16; ps++){
      int idx = ps*256 + t;
      adjs[idx>>6][idx&63] = Ab[idx];
    }
    if(t < 64){
      sl[t] = a.labels[a.knn[b*64 + t]];
      sn[t] = 1.0f / fmaxf(a.norms[b*64 + t], 1e-30f);
    }
    int qidx = a.indexes[b];
    int d = g*512 + t*2;
    float q0, q1;
    if(a.ff){
      float2 qv = *(const float2*)((const float*)a.feat + (size_t)qidx*DD + d);
      q0 = qv.x; q1 = qv.y;
    } else {
      u32 w = *(const u32*)((const u16*)a.feat + (size_t)qidx*DD + d);
      q0 = bf2f(w & 0xffffu); q1 = bf2f(w >> 16);
    }
    __syncthreads();
    if(t < 64){
      int c = 0;
      for(int j=0;j<64;j++){
        float v = adjs[t][j];
        if(v != 0.0f && c < 8){ nzv[t][c] = v; nzj[t][c] = (u16)j; c++; }
      }
      nzc[t] = c;
    }
    float inv0 = sn[0];
    q0 *= inv0; q1 *= inv0;
    // phase 1: thread t owns dims (d,d+1) of every x row
    *(u32*)(a.xab + (size_t)(b*64)*K2 + d) = 0u;
    for(int k=1;k<64;k++){
      float2 cv = *(const float2*)(a.clu + (size_t)sl[k]*DD + d);
      float invk = sn[k];
      u16 x0 = f2bf(cv.x*invk - q0), x1 = f2bf(cv.y*invk - q1);
      *(u32*)(a.xab + (size_t)(b*64+k)*K2 + d) = (u32)x0 | ((u32)x1 << 16);
    }
    __syncthreads();   // nz arrays; x reads below are same-thread RAW
    for(int r=0;r<64;r++){
      float a0 = 0.f, a1 = 0.f;
      int c = nzc[r];
      for(int p=0;p<c;p++){
        float s = nzv[r][p]; int j = nzj[r][p];
        u32 w = *(const u32*)(a.xab + (size_t)(b*64+j)*K2 + d);
        a0 += s*bf2f(w & 0xffffu);
        a1 += s*bf2f(w >> 16);
      }
      *(u32*)(a.xab + (size_t)(b*64+r)*K2 + DD + d) = (u32)f2bf(a0) | ((u32)f2bf(a1) << 16);
    }
  }
  grid.sync();

  // ---- P8 + P9: two MFMA GEMMs (512 tiles each) ----
  #pragma unroll 1
  for(int pass=0; pass<2; pass++){
    const u16* Am = pass==0 ? a.xab : a.hb;
    const u16* Bt = pass==0 ? a.cwT : a.w1T;
    int Kd = pass==0 ? K2 : NH;
    int fbias = pass==0 ? a.fcb : a.fb1;
    const void* bias = pass==0 ? a.conv_b : a.b1;
    u16 (*As)[4096] = (u16(*)[4096])smem;
    u16 (*Bs)[4096] = (u16(*)[4096])(smem + 16384);
    int bid = (gid & 7)*64 + (gid >> 3);   // XCD chunking, nblk=512
    int m0 = (bid >> 3) << 6;
    int n0 = (bid & 7) << 6;
    int wave = t >> 6, lane = t & 63;
    int wm = wave >> 1, wn = wave & 1;
    int lm = lane & 15, lq = lane >> 4;
    int lrow = lane >> 3, lcol = lane & 7;
    f32x4 acc[2][2];
    #pragma unroll
    for(int i=0;i<2;i++)
      #pragma unroll
      for(int j=0;j<2;j++) acc[i][j] = (f32x4){0.f,0.f,0.f,0.f};
    #define STAGE(buf, kb) do{ \
      _Pragma("unroll") \
      for(int c=0;c<2;c++){ \
        int cb = wave*2 + c; \
        int row = cb*8 + lrow; \
        int col = lcol ^ (row & 7); \
        glds16(Am + (size_t)(m0+row)*Kd + (kb) + col*8, &As[buf][cb*512]); \
      } \
      _Pragma("unroll") \
      for(int c=0;c<2;c++){ \
        int cb = wave*2 + c; \
        int row = cb*8 + lrow; \
        int col = lcol ^ (row & 7); \
        glds16(Bt + (size_t)(n0+row)*Kd + (kb) + col*8, &Bs[buf][cb*512]); \
      } \
    }while(0)
    STAGE(0, 0);
    __syncthreads();
    int cur = 0;
    for(int kb=0; kb<Kd; kb+=64){
      if(kb + 64 < Kd) STAGE(cur^1, kb+64);
      #pragma unroll
      for(int kk=0;kk<2;kk++){
        short8 af[2], bfr[2];
        #pragma unroll
        for(int mi=0;mi<2;mi++){
          int r = wm*32 + mi*16 + lm;
          int p = ((kk<<2)+lq) ^ (r & 7);
          union{ uint4 u; short8 v; } x;
          x.u = *(const uint4*)&As[cur][r*64 + p*8];
          af[mi] = x.v;
        }
        #pragma unroll
        for(int ni=0;ni<2;ni++){
          int r = wn*32 + ni*16 + lm;
          int p = ((kk<<2)+lq) ^ (r & 7);
          union{ uint4 u; short8 v; } x;
          x.u = *(const uint4*)&Bs[cur][r*64 + p*8];
          bfr[ni] = x.v;
        }
        #pragma unroll
        for(int mi=0;mi<2;mi++)
          #pragma unroll
          for(int ni=0;ni<2;ni++)
            acc[mi][ni] = __builtin_amdgcn_mfma_f32_16x16x32_bf16(af[mi], bfr[ni], acc[mi][ni], 0, 0, 0);
      }
      __syncthreads();
      cur ^= 1;
    }
    #undef STAGE
    #pragma unroll
    for(int ni=0;ni<2;ni++){
      int col = n0 + wn*32 + ni*16 + lm;
      float bs = fbias ? ((const float*)bias)[col] : bf2f(((const u16*)bias)[col]);
      float av = 0.f;
      if(pass==1) av = a.fpa ? ((const float*)a.pa)[col] : bf2f(((const u16*)a.pa)[col]);
      #pragma unroll
      for(int mi=0;mi<2;mi++){
        int rowb = m0 + wm*32 + mi*16 + lq*4;
        #pragma unroll
        for(int r2=0;r2<4;r2++){
          float v = acc[mi][ni][r2] + bs;
          if(pass==0){
            v = fmaxf(v, 0.f);
            a.hb[(size_t)(rowb+r2)*NH + col] = f2bf(v);
          } else {
            v = (v > 0.f) ? v : av*v;
            a.h1[(size_t)(rowb+r2)*NH + col] = v;
          }
        }
      }
    }
    grid.sync();
  }

  // ---- P10: logits + softmax ----
  for(int u = gid; u < 1024; u += 512){
    int lane = t & 63; int row = u*4 + (t >> 6);
    const float* hr = a.h1 + (size_t)row*NH;
    float s0 = 0.f, s1 = 0.f;
    #pragma unroll
    for(int j=0;j<NH/64;j++){
      int i = lane + j*64;
      float h = hr[i];
      float w0 = a.fw2 ? ((const float*)a.w2)[i*2+0] : bf2f(((const u16*)a.w2)[i*2+0]);
      float w1v= a.fw2 ? ((const float*)a.w2)[i*2+1] : bf2f(((const u16*)a.w2)[i*2+1]);
      s0 += h * w0;
      s1 += h * w1v;
    }
    #pragma unroll
    for(int off=32; off>0; off>>=1){
      s0 += __shfl_down(s0, off);
      s1 += __shfl_down(s1, off);
    }
    if(lane==0){
      float bb0 = a.fb2 ? ((const float*)a.b2)[0] : bf2f(((const u16*)a.b2)[0]);
      float bb1 = a.fb2 ? ((const float*)a.b2)[1] : bf2f(((const u16*)a.b2)[1]);
      float l0 = s0 + bb0;
      float l1 = s1 + bb1;
      float m = fmaxf(l0, l1);
      float e0 = expf(l0 - m), e1 = expf(l1 - m);
      float inv = 1.0f / (e0 + e1);
      if(a.fo){
        ((float*)a.out)[row*2+0] = e0*inv;
        ((float*)a.out)[row*2+1] = e1*inv;
      } else {
        ((u16*)a.out)[row*2+0] = f2bf(e0*inv);
        ((u16*)a.out)[row*2+1] = f2bf(e1*inv);
      }
    }
  }
}

// ======================= fallback path (round-3 kernels, verified) =======================
__global__ __launch_bounds__(256) void k_prep(
    const int* __restrict__ labels, int* __restrict__ counts,
    const int* __restrict__ knn, int* __restrict__ used,
    const void* __restrict__ conv_w, u16* __restrict__ cwT, int fcw,
    const void* __restrict__ w1, u16* __restrict__ w1T, int fw1){
  __shared__ u16 tile[64][65];
  int bb = blockIdx.x, t = threadIdx.x;
  if(bb < 128){
    int n = bb*256 + t;
    atomicAdd(&counts[labels[n]], 1);
    return;
  }
  if(bb == 704){
    #pragma unroll
    for(int i=0;i<16;i++){
      int idx = i*256 + t;
      used[labels[knn[idx]]] = 1;
    }
    return;
  }
  const void* src; u16* dst; int Kd, Nd, isf32, tb;
  if(bb < 640){ src=conv_w; dst=cwT; Kd=K2; Nd=NH; isf32=fcw; tb=bb-128; }
  else        { src=w1;     dst=w1T; Kd=NH; Nd=NH; isf32=fw1; tb=bb-640; }
  int nbt = Nd >> 6;
  int k0 = (tb / nbt) << 6;
  int n0 = (tb % nbt) << 6;
  if(isf32){
    const float* s = (const float*)src;
    #pragma unroll
    for(int ph=0; ph<16; ph++){
      int idx = ph*256 + t;
      int r = idx >> 6, c = idx & 63;
      tile[r][c] = f2bf(s[(size_t)(k0+r)*Nd + n0 + c]);
    }
  } else {
    const u16* s = (const u16*)src;
    #pragma unroll
    for(int ph=0; ph<16; ph++){
      int idx = ph*256 + t;
      int r = idx >> 6, c = idx & 63;
      tile[r][c] = s[(size_t)(k0+r)*Nd + n0 + c];
    }
  }
  __syncthreads();
  #pragma unroll
  for(int ph=0; ph<16; ph++){
    int idx = ph*256 + t;
    int r = idx >> 6, c = idx & 63;
    dst[(size_t)(n0+r)*Kd + k0 + c] = tile[c][r];
  }
}

__global__ void k_scan(const int* __restrict__ counts, int* __restrict__ offsets){
  __shared__ int sb[256];
  int t = threadIdx.x;
  int c[8]; int s = 0;
  #pragma unroll
  for(int i=0;i<8;i++){ c[i] = counts[t*8+i]; s += c[i]; }
  sb[t] = s; __syncthreads();
  int v = s;
  for(int off=1; off<256; off<<=1){
    int u = (t>=off) ? sb[t-off] : 0;
    __syncthreads();
    v += u; sb[t] = v;
    __syncthreads();
  }
  int run = v - s;
  #pragma unroll
  for(int i=0;i<8;i++){ offsets[t*8+i] = run; run += c[i]; }
}

__global__ void k_scatter(const int* __restrict__ labels, const int* __restrict__ offsets,
                          int* __restrict__ cursor, int* __restrict__ sorted){
  int n = blockIdx.x*256 + threadIdx.x;
  int c = labels[n];
  int p = atomicAdd(&cursor[c], 1);
  sorted[offsets[c] + p] = n;
}

__global__ __launch_bounds__(256) void k_clumean(
    const void* __restrict__ feat, const int* __restrict__ counts,
    const int* __restrict__ offsets, const int* __restrict__ sorted,
    const int* __restrict__ used, int isf32, float* __restrict__ clu){
  int c = blockIdx.x, t = threadIdx.x;
  if(!used[c]) return;
  __shared__ int ridx[64];
  int cnt = counts[c], start = offsets[c];
  float acc[8] = {0,0,0,0,0,0,0,0};
  for(int base=0; base<cnt; base+=64){
    int take = min(64, cnt-base);
    __syncthreads();
    if(t < take) ridx[t] = sorted[start+base+t];
    __syncthreads();
    if(isf32){
      const float* ff = (const float*)feat;
      int r = 0;
      for(; r+2<=take; r+=2){
        const float* p0 = ff + (size_t)ridx[r]*DD + t*8;
        const float* p1 = ff + (size_t)ridx[r+1]*DD + t*8;
        float4 a0=*(const float4*)p0, b0=*(const float4*)(p0+4);
        float4 a1=*(const float4*)p1, b1=*(const float4*)(p1+4);
        acc[0]+=a0.x+a1.x; acc[1]+=a0.y+a1.y; acc[2]+=a0.z+a1.z; acc[3]+=a0.w+a1.w;
        acc[4]+=b0.x+b1.x; acc[5]+=b0.y+b1.y; acc[6]+=b0.z+b1.z; acc[7]+=b0.w+b1.w;
      }
      if(r < take){
        const float* p0 = ff + (size_t)ridx[r]*DD + t*8;
        float4 a0=*(const float4*)p0, b0=*(const float4*)(p0+4);
        acc[0]+=a0.x; acc[1]+=a0.y; acc[2]+=a0.z; acc[3]+=a0.w;
        acc[4]+=b0.x; acc[5]+=b0.y; acc[6]+=b0.z; acc[7]+=b0.w;
      }
    } else {
      const u16* fb = (const u16*)feat;
      for(int r=0; r<take; r++){
        const u16* p0 = fb + (size_t)ridx[r]*DD + t*8;
        uint4 v0 = *(const uint4*)p0;
        acc[0]+=bf2f(v0.x&0xffffu); acc[1]+=bf2f(v0.x>>16);
        acc[2]+=bf2f(v0.y&0xffffu); acc[3]+=bf2f(v0.y>>16);
        acc[4]+=bf2f(v0.z&0xffffu); acc[5]+=bf2f(v0.z>>16);
        acc[6]+=bf2f(v0.w&0xffffu); acc[7]+=bf2f(v0.w>>16);
      }
    }
  }
  float div = fmaxf((float)cnt, 1.0f);
  float* o = clu + (size_t)c*DD + t*8;
  float4 o0 = make_float4(acc[0]/div, acc[1]/div, acc[2]/div, acc[3]/div);
  float4 o1 = make_float4(acc[4]/div, acc[5]/div, acc[6]/div, acc[7]/div);
  *(float4*)o = o0;
  *(float4*)(o+4) = o1;
}

__global__ __launch_bounds__(256) void k_Apart(
    const void* __restrict__ feat, const float* __restrict__ clu,
    const int* __restrict__ indexes, const int* __restrict__ labels,
    const int* __restrict__ knn, int isf32, float* __restrict__ Apart){
  int b = blockIdx.x >> 2, g = blockIdx.x & 3;
  int t = threadIdx.x;
  __shared__ float cfT[64][68];
  __shared__ int sl[64];
  if(t < 64) sl[t] = labels[knn[b*64 + t]];
  int qidx = indexes[b];
  __syncthreads();
  int i0 = (t & 15)*4, j0 = (t >> 4)*4;
  float acc[4][4];
  #pragma unroll
  for(int x=0;x<4;x++)
    #pragma unroll
    for(int c2=0;c2<4;c2++) acc[x][c2] = 0.f;
  for(int ch=g*8; ch<g*8+8; ch++){
    int dbase = ch*64;
    #pragma unroll
    for(int ps=0; ps<16; ps++){
      int idx = ps*256 + t;
      int k = idx >> 6, dd = idx & 63;
      float v;
      if(k == 0){
        size_t fi = (size_t)qidx*DD + dbase + dd;
        v = isf32 ? ((const float*)feat)[fi] : bf2f(((const u16*)feat)[fi]);
      } else {
        v = clu[(size_t)sl[k]*DD + dbase + dd];
      }
      cfT[dd][k] = v;
    }
    __syncthreads();
    #pragma unroll 4
    for(int dd=0; dd<64; dd++){
      float4 av = *(const float4*)&cfT[dd][i0];
      float4 bv = *(const float4*)&cfT[dd][j0];
      float aa[4] = {av.x, av.y, av.z, av.w};
      float bbv[4] = {bv.x, bv.y, bv.z, bv.w};
      #pragma unroll
      for(int ii=0;ii<4;ii++)
        #pragma unroll
        for(int jj=0;jj<4;jj++)
          acc[ii][jj] += aa[ii]*bbv[jj];
    }
    __syncthreads();
  }
  float* op = Apart + ((size_t)(g*64 + b))*4096;
  #pragma unroll
  for(int ii=0;ii<4;ii++)
    *(float4*)&op[(i0+ii)*64 + j0] = make_float4(acc[ii][0], acc[ii][1], acc[ii][2], acc[ii][3]);
}

__global__ __launch_bounds__(256) void k_Afinal(
    const float* __restrict__ Apart, const int* __restrict__ labels,
    const int* __restrict__ knn,
    float* __restrict__ adj, float* __restrict__ norms){
  int b = blockIdx.x, t = threadIdx.x;
  __shared__ float A[64][65];
  __shared__ unsigned long long mb[64];
  __shared__ int sl[64];
  __shared__ int sk[64];
  if(t < 64) sl[t] = labels[knn[b*64 + t]];
  const float* P = Apart + (size_t)b*4096;
  const size_t gs = (size_t)64*4096;
  #pragma unroll
  for(int ps=0; ps<16; ps++){
    int idx = ps*256 + t;
    float s = P[idx] + P[idx+gs] + P[idx+2*gs] + P[idx+3*gs];
    A[idx>>6][idx&63] = s * 0.2f;
  }
  __syncthreads();
  if(t < 64){
    int dup = 0;
    for(int j=0;j<t;j++) dup |= (sl[j]==sl[t]);
    sk[t] = dup ? 0 : 1;
    unsigned long long chosen = 0;
    const float* row = A[t];
    #pragma unroll
    for(int p=0;p<5;p++){
      float best = -INFINITY; int bi = 0;
      for(int j=0;j<64;j++){
        bool taken = (chosen >> j) & 1ull;
        float v = row[j];
        if(!taken && v > best){ best = v; bi = j; }
      }
      chosen |= (1ull << bi);
    }
    mb[t] = chosen;
    norms[b*64+t] = sqrtf(fmaxf(A[t][t]*5.0f, 0.0f));
  }
  __syncthreads();
  float* O = adj + (size_t)b*4096;
  #pragma unroll
  for(int ps=0; ps<16; ps++){
    int idx = ps*256 + t;
    int i = idx >> 6, j = idx & 63;
    bool on = ((mb[i]>>j)&1ull) && ((mb[j]>>i)&1ull) && sk[i] && sk[j];
    O[idx] = on ? A[i][j] : 0.0f;
  }
}

__global__ __launch_bounds__(256) void k_xagg(
    const void* __restrict__ feat, const float* __restrict__ clu,
    const int* __restrict__ indexes, const int* __restrict__ labels,
    const int* __restrict__ knn, const float* __restrict__ norms,
    const float* __restrict__ adj, int isf32, u16* __restrict__ xab){
  int b = blockIdx.x >> 2, g = blockIdx.x & 3;
  int t = threadIdx.x;
  __shared__ u16  xs[64][512];
  __shared__ float adjs[64][65];
  __shared__ float nzv[64][8];
  __shared__ u16   nzj[64][8];
  __shared__ int   nzc[64];
  __shared__ int   sl[64];
  __shared__ float sn[64];
  const float* Ab = adj + (size_t)b*4096;
  #pragma unroll
  for(int ps=0; ps<16; ps++){
    int idx = ps*256 + t;
    adjs[idx>>6][idx&63] = Ab[idx];
  }
  if(t < 64){
    sl[t] = labels[knn[b*64 + t]];
    sn[t] = 1.0f / fmaxf(norms[b*64 + t], 1e-30f);
  }
  int qidx = indexes[b];
  int d = g*512 + t*2;
  float q0, q1;
  if(isf32){
    float2 qv = *(const float2*)((const float*)feat + (size_t)qidx*DD + d);
    q0 = qv.x; q1 = qv.y;
  } else {
    u32 w = *(const u32*)((const u16*)feat + (size_t)qidx*DD + d);
    q0 = bf2f(w & 0xffffu); q1 = bf2f(w >> 16);
  }
  __syncthreads();
  if(t < 64){
    int c = 0;
    for(int j=0;j<64;j++){
      float v = adjs[t][j];
      if(v != 0.0f && c < 8){ nzv[t][c] = v; nzj[t][c] = (u16)j; c++; }
    }
    nzc[t] = c;
  }
  float inv0 = sn[0];
  q0 *= inv0; q1 *= inv0;
  *(u32*)&xs[0][t*2] = 0u;
  *(u32*)(xab + (size_t)(b*64)*K2 + d) = 0u;
  for(int k=1;k<64;k++){
    float2 cv = *(const float2*)(clu + (size_t)sl[k]*DD + d);
    float invk = sn[k];
    u16 x0 = f2bf(cv.x*invk - q0), x1 = f2bf(cv.y*invk - q1);
    u32 w = (u32)x0 | ((u32)x1 << 16);
    *(u32*)&xs[k][t*2] = w;
    *(u32*)(xab + (size_t)(b*64+k)*K2 + d) = w;
  }
  __syncthreads();
  for(int r=0;r<64;r++){
    float a0 = 0.f, a1 = 0.f;
    int c = nzc[r];
    for(int p=0;p<c;p++){
      float s = nzv[r][p]; int j = nzj[r][p];
      u32 w = *(const u32*)&xs[j][t*2];
      a0 += s*bf2f(w & 0xffffu);
      a1 += s*bf2f(w >> 16);
    }
    u32 w = (u32)f2bf(a0) | ((u32)f2bf(a1) << 16);
    *(u32*)(xab + (size_t)(b*64+r)*K2 + DD + d) = w;
  }
}

template<int EPI>
__global__ __launch_bounds__(256, 2) void k_gemm(
    const u16* __restrict__ Am, const u16* __restrict__ Bt,
    const void* __restrict__ bias, const void* __restrict__ pa,
    int fbias, int fpa,
    void* __restrict__ Cout, int Md, int Nd, int Kd)
{
  __shared__ u16 As[2][64*64];
  __shared__ u16 Bs[2][64*64];
  int t = threadIdx.x;
  int nblk = gridDim.x;
  int bid = (blockIdx.x & 7)*(nblk >> 3) + (blockIdx.x >> 3);
  int nb = Nd >> 6;
  int m0 = (bid / nb) << 6;
  int n0 = (bid % nb) << 6;
  int wave = t >> 6, lane = t & 63;
  int wm = wave >> 1, wn = wave & 1;
  int lm = lane & 15, lq = lane >> 4;
  int lrow = lane >> 3, lcol = lane & 7;
  f32x4 acc[2][2];
  #pragma unroll
  for(int i=0;i<2;i++)
    #pragma unroll
    for(int j=0;j<2;j++) acc[i][j] = (f32x4){0.f,0.f,0.f,0.f};
  auto stage = [&](int buf, int kb){
    #pragma unroll
    for(int c=0;c<2;c++){
      int cb = wave*2 + c;
      int row = cb*8 + lrow;
      int col = lcol ^ (row & 7);
      glds16(Am + (size_t)(m0+row)*Kd + kb + col*8, &As[buf][cb*512]);
    }
    #pragma unroll
    for(int c=0;c<2;c++){
      int cb = wave*2 + c;
      int row = cb*8 + lrow;
      int col = lcol ^ (row & 7);
      glds16(Bt + (size_t)(n0+row)*Kd + kb + col*8, &Bs[buf][cb*512]);
    }
  };
  stage(0, 0);
  __syncthreads();
  int cur = 0;
  for(int kb=0; kb<Kd; kb+=64){
    if(kb + 64 < Kd) stage(cur^1, kb+64);
    #pragma unroll
    for(int kk=0;kk<2;kk++){
      short8 af[2], bfr[2];
      #pragma unroll
      for(int mi=0;mi<2;mi++){
        int r = wm*32 + mi*16 + lm;
        int p = ((kk<<2)+lq) ^ (r & 7);
        union{ uint4 u; short8 v; } x;
        x.u = *(const uint4*)&As[cur][r*64 + p*8];
        af[mi] = x.v;
      }
      #pragma unroll
      for(int ni=0;ni<2;ni++){
        int r = wn*32 + ni*16 + lm;
        int p = ((kk<<2)+lq) ^ (r & 7);
        union{ uint4 u; short8 v; } x;
        x.u = *(const uint4*)&Bs[cur][r*64 + p*8];
        bfr[ni] = x.v;
      }
      #pragma unroll
      for(int mi=0;mi<2;mi++)
        #pragma unroll
        for(int ni=0;ni<2;ni++)
          acc[mi][ni] = __builtin_amdgcn_mfma_f32_16x16x32_bf16(af[mi], bfr[ni], acc[mi][ni], 0, 0, 0);
    }
    __syncthreads();
    cur ^= 1;
  }
  #pragma unroll
  for(int ni=0;ni<2;ni++){
    int col = n0 + wn*32 + ni*16 + lm;
    float bs = fbias ? ((const float*)bias)[col] : bf2f(((const u16*)bias)[col]);
    float av = 0.f;
    if(EPI==1) av = fpa ? ((const float*)pa)[col] : bf2f(((const u16*)pa)[col]);
    #pragma unroll
    for(int mi=0;mi<2;mi++){
      int rowb = m0 + wm*32 + mi*16 + lq*4;
      #pragma unroll
      for(int r2=0;r2<4;r2++){
        float v = acc[mi][ni][r2] + bs;
        if(EPI==0){
          v = fmaxf(v, 0.f);
          ((u16*)Cout)[(size_t)(rowb+r2)*Nd + col] = f2bf(v);
        } else {
          v = (v > 0.f) ? v : av*v;
          ((float*)Cout)[(size_t)(rowb+r2)*Nd + col] = v;
        }
      }
    }
  }
}

__global__ __launch_bounds__(256) void k_out(
    const float* __restrict__ h1, const void* __restrict__ w2,
    const void* __restrict__ b2, int fw2, int fb2, int fo,
    void* __restrict__ out){
  int t = threadIdx.x; int lane = t & 63; int row = blockIdx.x*4 + (t >> 6);
  const float* hr = h1 + (size_t)row*NH;
  float s0 = 0.f, s1 = 0.f;
  #pragma unroll
  for(int j=0;j<NH/64;j++){
    int i = lane + j*64;
    float h = hr[i];
    float w0 = fw2 ? ((const float*)w2)[i*2+0] : bf2f(((const u16*)w2)[i*2+0]);
    float w1v= fw2 ? ((const float*)w2)[i*2+1] : bf2f(((const u16*)w2)[i*2+1]);
    s0 += h * w0;
    s1 += h * w1v;
  }
  #pragma unroll
  for(int off=32; off>0; off>>=1){
    s0 += __shfl_down(s0, off);
    s1 += __shfl_down(s1, off);
  }
  if(lane==0){
    float bb0 = fb2 ? ((const float*)b2)[0] : bf2f(((const u16*)b2)[0]);
    float bb1 = fb2 ? ((const float*)b2)[1] : bf2f(((const u16*)b2)[1]);
    float l0 = s0 + bb0;
    float l1 = s1 + bb1;
    float m = fmaxf(l0, l1);
    float e0 = expf(l0 - m), e1 = expf(l1 - m);
    float inv = 1.0f / (e0 + e1);
    if(fo){
      ((float*)out)[row*2+0] = e0*inv;
      ((float*)out)[row*2+1] = e1*inv;
    } else {
      ((u16*)out)[row*2+0] = f2bf(e0*inv);
      ((u16*)out)[row*2+1] = f2bf(e1*inv);
    }
  }
}

__global__ void k_fill_sentinel(u32* __restrict__ out, int nwords){
  int i = blockIdx.x*256 + threadIdx.x;
  if(i < nwords) out[i] = 0x40404040u;
}

extern "C" void kernel_launch(void* const* d_in, const int* in_sizes, int n_in,
                              void* d_out, int out_size, void* d_ws, size_t ws_size,
                              hipStream_t stream) {
  const int* indexes = (const int*)d_in[0];
  const void* feat   = d_in[1];
  const int* labels  = (const int*)d_in[2];
  const int* knn     = (const int*)d_in[3];
  const void* conv_w = d_in[4];
  const void* conv_b = d_in[5];
  const void* w1     = d_in[6];
  const void* b1     = d_in[7];
  const void* pa     = d_in[8];
  const void* w2     = d_in[9];
  const void* b2     = d_in[10];

  int ff  = (in_sizes[1]  != (int)((size_t)NPTS*DD*2));
  int fcw = (in_sizes[4]  != (int)((size_t)2*DD*NH*2));
  int fcb = (in_sizes[5]  != NH*2);
  int fw1 = (in_sizes[6]  != (int)((size_t)NH*NH*2));
  int fb1 = (in_sizes[7]  != NH*2);
  int fpa = (in_sizes[8]  != NH*2);
  int fw2 = (in_sizes[9]  != NH*2*2);
  int fb2 = (in_sizes[10] != 2*2);
  int fo  = (out_size     != MM*2*2);

  char* w = (char*)d_ws;
  size_t o = 0;
  auto alloc = [&](size_t bytes) -> void* {
    void* p = w + o; o = (o + bytes + 255) & ~(size_t)255; return p;
  };
  int*   counts  = (int*)  alloc((size_t)NCC*4);
  int*   cursor  = (int*)  alloc((size_t)NCC*4);
  int*   used    = (int*)  alloc((size_t)NCC*4);
  int*   offsets = (int*)  alloc((size_t)NCC*4);
  int*   sorted  = (int*)  alloc((size_t)NPTS*4);
  float* norms   = (float*)alloc((size_t)MM*4);
  float* adj     = (float*)alloc((size_t)BB*64*64*4);
  float* Apart   = (float*)alloc((size_t)8*BB*64*64*4);  // 8 MB (8 dgroups)
  float* clu     = (float*)alloc((size_t)NCC*DD*4);
  u16*   xab     = (u16*)  alloc((size_t)MM*K2*2);
  u16*   cwT     = (u16*)  alloc((size_t)K2*NH*2);
  u16*   w1T     = (u16*)  alloc((size_t)NH*NH*2);
  u16*   hb      = (u16*)  clu;
  float* h1      = (float*)((char*)clu + (size_t)MM*NH*2);

  size_t NEED = o;
  if(ws_size < NEED){
    int nwords = out_size/4;
    k_fill_sentinel<<<(nwords+255)/256, 256, 0, stream>>>((u32*)d_out, nwords);
    return;
  }

  MegaArgs ma;
  ma.indexes=indexes; ma.feat=feat; ma.labels=labels; ma.knn=knn;
  ma.conv_w=conv_w; ma.conv_b=conv_b; ma.w1=w1; ma.b1=b1;
  ma.pa=pa; ma.w2=w2; ma.b2=b2;
  ma.ff=ff; ma.fcw=fcw; ma.fcb=fcb; ma.fw1=fw1; ma.fb1=fb1;
  ma.fpa=fpa; ma.fw2=fw2; ma.fb2=fb2; ma.fo=fo;
  ma.counts=counts; ma.cursor=cursor; ma.used=used; ma.offsets=offsets;
  ma.sorted=sorted; ma.norms=norms; ma.adj=adj; ma.Apart=Apart; ma.clu=clu;
  ma.xab=xab; ma.cwT=cwT; ma.w1T=w1T; ma.hb=hb; ma.h1=h1; ma.out=d_out;

  void* kargs[] = { &ma };
  hipError_t e = hipLaunchCooperativeKernel((const void*)k_mega, dim3(512), dim3(256),
                                            kargs, 0, stream);
  if(e != hipSuccess){
    // fallback: verified round-3 multi-kernel path
    hipMemsetAsync(counts, 0, (size_t)NCC*4*3, stream);
    k_prep   <<<705, 256, 0, stream>>>(labels, counts, knn, used, conv_w, cwT, fcw, w1, w1T, fw1);
    k_scan   <<<1, 256, 0, stream>>>(counts, offsets);
    k_scatter<<<NPTS/256, 256, 0, stream>>>(labels, offsets, cursor, sorted);
    k_clumean<<<NCC, 256, 0, stream>>>(feat, counts, offsets, sorted, used, ff, clu);
    k_Apart  <<<BB*4, 256, 0, stream>>>(feat, clu, indexes, labels, knn, ff, Apart);
    k_Afinal <<<BB, 256, 0, stream>>>(Apart, labels, knn, adj, norms);
    k_xagg   <<<BB*4, 256, 0, stream>>>(feat, clu, indexes, labels, knn, norms, adj, ff, xab);
    k_gemm<0><<<(MM/64)*(NH/64), 256, 0, stream>>>(xab, cwT, conv_b, nullptr, fcb, 0, (void*)hb, MM, NH, K2);
    k_gemm<1><<<(MM/64)*(NH/64), 256, 0, stream>>>(hb, w1T, b1, pa, fb1, fpa, (void*)h1, MM, NH, NH);
    k_out    <<<MM/4, 256, 0, stream>>>(h1, w2, b2, fw2, fb2, fo, d_out);
  }
}

// Round 5
// 533.949 us; speedup vs baseline: 2.2075x; 2.2075x over previous
//
#include <hip/hip_runtime.h>
#include <hip/hip_bf16.h>

#define BB 64
#define KN 64
#define NPTS 32768
#define DD 2048
#define NCC 2048
#define NH 512
#define MM 4096   /* BB*KN */
#define K2 4096   /* 2*DD  */

typedef unsigned short u16;
typedef unsigned int u32;
typedef __attribute__((ext_vector_type(8))) short short8;
typedef __attribute__((ext_vector_type(4))) float f32x4;

__device__ __forceinline__ float bf2f(u32 u){
  union { u32 i; float f; } v; v.i = u << 16; return v.f;
}
__device__ __forceinline__ u16 f2bf(float f){
  union { float f; u32 i; } v; v.f = f;
  u32 x = v.i;
  return (u16)((x + 0x7fffu + ((x >> 16) & 1u)) >> 16);
}

// global_load_lds: per-lane global src, wave-uniform LDS base (+lane*16 by HW)
typedef __attribute__((address_space(3))) u32 as3_u32;
typedef const __attribute__((address_space(1))) u32 as1_u32;
__device__ __forceinline__ void glds16(const void* g, void* l){
  __builtin_amdgcn_global_load_lds((as1_u32*)g, (as3_u32*)l, 16, 0, 0);
}

// ---------------- fused prep: label count + used-cluster mark + weight transposes ----------------
__global__ __launch_bounds__(256) void k_prep(
    const int* __restrict__ labels, int* __restrict__ counts,
    const int* __restrict__ knn, int* __restrict__ used,
    const void* __restrict__ conv_w, u16* __restrict__ cwT, int fcw,
    const void* __restrict__ w1, u16* __restrict__ w1T, int fw1){
  __shared__ u16 tile[64][65];
  int bb = blockIdx.x, t = threadIdx.x;
  if(bb < 128){
    int n = bb*256 + t;
    atomicAdd(&counts[labels[n]], 1);
    return;
  }
  if(bb == 704){
    #pragma unroll
    for(int i=0;i<16;i++){
      int idx = i*256 + t;           // 4096 knn entries
      used[labels[knn[idx]]] = 1;    // benign race: all write 1
    }
    return;
  }
  const void* src; u16* dst; int Kd, Nd, isf32, tb;
  if(bb < 640){ src=conv_w; dst=cwT; Kd=K2; Nd=NH; isf32=fcw; tb=bb-128; }
  else        { src=w1;     dst=w1T; Kd=NH; Nd=NH; isf32=fw1; tb=bb-640; }
  int nbt = Nd >> 6;
  int k0 = (tb / nbt) << 6;
  int n0 = (tb % nbt) << 6;
  if(isf32){
    const float* s = (const float*)src;
    #pragma unroll
    for(int ph=0; ph<16; ph++){
      int idx = ph*256 + t;
      int r = idx >> 6, c = idx & 63;
      tile[r][c] = f2bf(s[(size_t)(k0+r)*Nd + n0 + c]);
    }
  } else {
    const u16* s = (const u16*)src;
    #pragma unroll
    for(int ph=0; ph<16; ph++){
      int idx = ph*256 + t;
      int r = idx >> 6, c = idx & 63;
      tile[r][c] = s[(size_t)(k0+r)*Nd + n0 + c];
    }
  }
  __syncthreads();
  #pragma unroll
  for(int ph=0; ph<16; ph++){
    int idx = ph*256 + t;
    int r = idx >> 6, c = idx & 63;
    dst[(size_t)(n0+r)*Kd + k0 + c] = tile[c][r];
  }
}

__global__ void k_scan(const int* __restrict__ counts, int* __restrict__ offsets){
  __shared__ int sb[256];
  int t = threadIdx.x;
  int c[8]; int s = 0;
  #pragma unroll
  for(int i=0;i<8;i++){ c[i] = counts[t*8+i]; s += c[i]; }
  sb[t] = s; __syncthreads();
  int v = s;
  for(int off=1; off<256; off<<=1){
    int u = (t>=off) ? sb[t-off] : 0;
    __syncthreads();
    v += u; sb[t] = v;
    __syncthreads();
  }
  int run = v - s;
  #pragma unroll
  for(int i=0;i<8;i++){ offsets[t*8+i] = run; run += c[i]; }
}

__global__ void k_scatter(const int* __restrict__ labels, const int* __restrict__ offsets,
                          int* __restrict__ cursor, int* __restrict__ sorted){
  int n = blockIdx.x*256 + threadIdx.x;
  int c = labels[n];
  int p = atomicAdd(&cursor[c], 1);
  sorted[offsets[c] + p] = n;
}

// ---------------- cluster means: LDS index prefetch, 4-row unroll, used-only ----------------
__global__ __launch_bounds__(256) void k_clumean(
    const void* __restrict__ feat, const int* __restrict__ counts,
    const int* __restrict__ offsets, const int* __restrict__ sorted,
    const int* __restrict__ used, int isf32, float* __restrict__ clu){
  int c = blockIdx.x, t = threadIdx.x;
  if(!used[c]) return;    // unused cluster means are never read
  __shared__ int ridx[64];
  int cnt = counts[c], start = offsets[c];
  float acc[8] = {0,0,0,0,0,0,0,0};
  for(int base=0; base<cnt; base+=64){
    int take = min(64, cnt-base);
    __syncthreads();
    if(t < take) ridx[t] = sorted[start+base+t];
    __syncthreads();
    if(isf32){
      const float* ff = (const float*)feat;
      int r = 0;
      for(; r+4<=take; r+=4){
        const float* p0 = ff + (size_t)ridx[r]*DD + t*8;
        const float* p1 = ff + (size_t)ridx[r+1]*DD + t*8;
        const float* p2 = ff + (size_t)ridx[r+2]*DD + t*8;
        const float* p3 = ff + (size_t)ridx[r+3]*DD + t*8;
        float4 a0=*(const float4*)p0, b0=*(const float4*)(p0+4);
        float4 a1=*(const float4*)p1, b1=*(const float4*)(p1+4);
        float4 a2=*(const float4*)p2, b2=*(const float4*)(p2+4);
        float4 a3=*(const float4*)p3, b3=*(const float4*)(p3+4);
        acc[0]+=a0.x+a1.x+a2.x+a3.x; acc[1]+=a0.y+a1.y+a2.y+a3.y;
        acc[2]+=a0.z+a1.z+a2.z+a3.z; acc[3]+=a0.w+a1.w+a2.w+a3.w;
        acc[4]+=b0.x+b1.x+b2.x+b3.x; acc[5]+=b0.y+b1.y+b2.y+b3.y;
        acc[6]+=b0.z+b1.z+b2.z+b3.z; acc[7]+=b0.w+b1.w+b2.w+b3.w;
      }
      for(; r<take; r++){
        const float* p0 = ff + (size_t)ridx[r]*DD + t*8;
        float4 a0=*(const float4*)p0, b0=*(const float4*)(p0+4);
        acc[0]+=a0.x; acc[1]+=a0.y; acc[2]+=a0.z; acc[3]+=a0.w;
        acc[4]+=b0.x; acc[5]+=b0.y; acc[6]+=b0.z; acc[7]+=b0.w;
      }
    } else {
      const u16* fb = (const u16*)feat;
      for(int r=0; r<take; r++){
        const u16* p0 = fb + (size_t)ridx[r]*DD + t*8;
        uint4 v0 = *(const uint4*)p0;
        acc[0]+=bf2f(v0.x&0xffffu); acc[1]+=bf2f(v0.x>>16);
        acc[2]+=bf2f(v0.y&0xffffu); acc[3]+=bf2f(v0.y>>16);
        acc[4]+=bf2f(v0.z&0xffffu); acc[5]+=bf2f(v0.z>>16);
        acc[6]+=bf2f(v0.w&0xffffu); acc[7]+=bf2f(v0.w>>16);
      }
    }
  }
  float div = fmaxf((float)cnt, 1.0f);
  float* o = clu + (size_t)c*DD + t*8;
  float4 o0 = make_float4(acc[0]/div, acc[1]/div, acc[2]/div, acc[3]/div);
  float4 o1 = make_float4(acc[4]/div, acc[5]/div, acc[6]/div, acc[7]/div);
  *(float4*)o = o0;
  *(float4*)(o+4) = o1;
}

// ---------------- partial A: block (b, dgroup g) accumulates 512 dims ----------------
__global__ __launch_bounds__(256) void k_Apart(
    const void* __restrict__ feat, const float* __restrict__ clu,
    const int* __restrict__ indexes, const int* __restrict__ labels,
    const int* __restrict__ knn, int isf32, float* __restrict__ Apart){
  int b = blockIdx.x >> 2, g = blockIdx.x & 3;
  int t = threadIdx.x;
  __shared__ float cfT[64][68];
  __shared__ int sl[64];
  if(t < 64) sl[t] = labels[knn[b*64 + t]];
  int qidx = indexes[b];
  __syncthreads();
  int i0 = (t & 15)*4, j0 = (t >> 4)*4;
  float acc[4][4];
  #pragma unroll
  for(int x=0;x<4;x++)
    #pragma unroll
    for(int c2=0;c2<4;c2++) acc[x][c2] = 0.f;
  for(int ch=g*8; ch<g*8+8; ch++){
    int dbase = ch*64;
    #pragma unroll
    for(int ps=0; ps<16; ps++){
      int idx = ps*256 + t;
      int k = idx >> 6, dd = idx & 63;
      float v;
      if(k == 0){
        size_t fi = (size_t)qidx*DD + dbase + dd;
        v = isf32 ? ((const float*)feat)[fi] : bf2f(((const u16*)feat)[fi]);
      } else {
        v = clu[(size_t)sl[k]*DD + dbase + dd];
      }
      cfT[dd][k] = v;
    }
    __syncthreads();
    #pragma unroll 4
    for(int dd=0; dd<64; dd++){
      float4 av = *(const float4*)&cfT[dd][i0];
      float4 bv = *(const float4*)&cfT[dd][j0];
      float aa[4] = {av.x, av.y, av.z, av.w};
      float bbv[4] = {bv.x, bv.y, bv.z, bv.w};
      #pragma unroll
      for(int ii=0;ii<4;ii++)
        #pragma unroll
        for(int jj=0;jj<4;jj++)
          acc[ii][jj] += aa[ii]*bbv[jj];
    }
    __syncthreads();
  }
  float* op = Apart + ((size_t)(g*64 + b))*4096;
  #pragma unroll
  for(int ii=0;ii<4;ii++)
    *(float4*)&op[(i0+ii)*64 + j0] = make_float4(acc[ii][0], acc[ii][1], acc[ii][2], acc[ii][3]);
}

// ---------------- final A: sum partials, keep mask, top-5, norms, adj ----------------
__global__ __launch_bounds__(256) void k_Afinal(
    const float* __restrict__ Apart, const int* __restrict__ labels,
    const int* __restrict__ knn,
    float* __restrict__ adj, float* __restrict__ norms){
  int b = blockIdx.x, t = threadIdx.x;
  __shared__ float A[64][65];
  __shared__ unsigned long long mb[64];
  __shared__ int sl[64];
  __shared__ int sk[64];
  if(t < 64) sl[t] = labels[knn[b*64 + t]];
  const float* P = Apart + (size_t)b*4096;
  const size_t gs = (size_t)64*4096;
  #pragma unroll
  for(int ps=0; ps<16; ps++){
    int idx = ps*256 + t;
    float s = P[idx] + P[idx+gs] + P[idx+2*gs] + P[idx+3*gs];
    A[idx>>6][idx&63] = s * 0.2f;
  }
  __syncthreads();
  if(t < 64){
    int dup = 0;
    for(int j=0;j<t;j++) dup |= (sl[j]==sl[t]);
    sk[t] = dup ? 0 : 1;
    unsigned long long chosen = 0;
    const float* row = A[t];
    #pragma unroll
    for(int p=0;p<5;p++){
      float best = -INFINITY; int bi = 0;
      for(int j=0;j<64;j++){
        bool taken = (chosen >> j) & 1ull;
        float v = row[j];
        if(!taken && v > best){ best = v; bi = j; }
      }
      chosen |= (1ull << bi);
    }
    mb[t] = chosen;
    norms[b*64+t] = sqrtf(fmaxf(A[t][t]*5.0f, 0.0f));
  }
  __syncthreads();
  float* O = adj + (size_t)b*4096;
  #pragma unroll
  for(int ps=0; ps<16; ps++){
    int idx = ps*256 + t;
    int i = idx >> 6, j = idx & 63;
    bool on = ((mb[i]>>j)&1ull) && ((mb[j]>>i)&1ull) && sk[i] && sk[j];
    O[idx] = on ? A[i][j] : 0.0f;
  }
}

// ---------------- fused x + agg: block (b, d-eighth g); x slice in LDS, sparse agg ----------------
// 8 dgroups (512 blocks, ~52 KB LDS -> 2 blocks/CU) for latency hiding.
__global__ __launch_bounds__(256) void k_xagg(
    const void* __restrict__ feat, const float* __restrict__ clu,
    const int* __restrict__ indexes, const int* __restrict__ labels,
    const int* __restrict__ knn, const float* __restrict__ norms,
    const float* __restrict__ adj, int isf32, u16* __restrict__ xab){
  int b = blockIdx.x >> 3, g = blockIdx.x & 7;
  int t = threadIdx.x;
  __shared__ u16  xs[64][256];    // 32 KB bf16 x-slice
  __shared__ float adjs[64][65];  // 16.25 KB staged adj
  __shared__ float nzv[64][8];
  __shared__ u16   nzj[64][8];
  __shared__ int   nzc[64];
  __shared__ int   sl[64];
  __shared__ float sn[64];

  const float* Ab = adj + (size_t)b*4096;
  #pragma unroll
  for(int ps=0; ps<16; ps++){
    int idx = ps*256 + t;
    adjs[idx>>6][idx&63] = Ab[idx];
  }
  if(t < 64){
    sl[t] = labels[knn[b*64 + t]];
    sn[t] = 1.0f / fmaxf(norms[b*64 + t], 1e-30f);
  }
  int qidx = indexes[b];
  int d = g*256 + t;                 // this thread's single dim
  float q0;
  if(isf32){
    q0 = ((const float*)feat)[(size_t)qidx*DD + d];
  } else {
    q0 = bf2f(((const u16*)feat)[(size_t)qidx*DD + d]);
  }
  __syncthreads();
  if(t < 64){                        // nonzero extraction from LDS adj row t
    int c = 0;
    for(int j=0;j<64;j++){
      float v = adjs[t][j];
      if(v != 0.0f && c < 8){ nzv[t][c] = v; nzj[t][c] = (u16)j; c++; }
    }
    nzc[t] = c;
  }
  q0 *= sn[0];

  // phase 1: x rows (row 0 is zero), write LDS + global
  xs[0][t] = 0;
  xab[(size_t)(b*64)*K2 + d] = 0;
  for(int k=1;k<64;k++){
    float cv = clu[(size_t)sl[k]*DD + d];
    u16 x0 = f2bf(cv*sn[k] - q0);
    xs[k][t] = x0;
    xab[(size_t)(b*64+k)*K2 + d] = x0;
  }
  __syncthreads();

  // phase 2: agg rows from sparse adj over LDS x
  for(int r=0;r<64;r++){
    float a0 = 0.f;
    int c = nzc[r];
    for(int p=0;p<c;p++){
      a0 += nzv[r][p] * bf2f(xs[nzj[r][p]][t]);
    }
    xab[(size_t)(b*64+r)*K2 + DD + d] = f2bf(a0);
  }
}

// ---------------- bf16 MFMA GEMM: C = epi(A @ Bt^T + bias), BM=BN=64, BK=128, 2/CU ----------------
// BK=128 halves vmcnt(0)-drain barriers vs BK=64. Swizzle: 16 chunks/row,
// physical chunk p = q ^ (row&7) (XOR of low 3 bits only -> bijective, same
// per-quarter bank distribution as verified BK=64 scheme).
template<int EPI>
__global__ __launch_bounds__(256, 2) void k_gemm(
    const u16* __restrict__ Am, const u16* __restrict__ Bt,
    const void* __restrict__ bias, const void* __restrict__ pa,
    int fbias, int fpa,
    void* __restrict__ Cout, int Md, int Nd, int Kd)
{
  __shared__ u16 As[2][64*128];
  __shared__ u16 Bs[2][64*128];
  int t = threadIdx.x;
  int nblk = gridDim.x;
  int bid = (blockIdx.x & 7)*(nblk >> 3) + (blockIdx.x >> 3);  // XCD chunking
  int nb = Nd >> 6;
  int m0 = (bid / nb) << 6;
  int n0 = (bid % nb) << 6;
  int wave = t >> 6, lane = t & 63;
  int wm = wave >> 1, wn = wave & 1;
  int lm = lane & 15, lq = lane >> 4;
  int lrow4 = lane >> 4, lcol16 = lane & 15;  // 4 rows x 16 chunks per glds pass

  f32x4 acc[2][2];
  #pragma unroll
  for(int i=0;i<2;i++)
    #pragma unroll
    for(int j=0;j<2;j++) acc[i][j] = (f32x4){0.f,0.f,0.f,0.f};

  // stage: linear LDS dest (glds writes base+16*lane), inverse-swizzled source.
  // chunk-block cb = 4 rows x 16 chunks = 1024 B. 16 cbs per tile, 4 per wave.
  auto stage = [&](int buf, int kb){
    #pragma unroll
    for(int c=0;c<4;c++){
      int cb = wave*4 + c;
      int row = cb*4 + lrow4;
      int col = lcol16 ^ (row & 7);
      glds16(Am + (size_t)(m0+row)*Kd + kb + col*8, &As[buf][cb*512]);
    }
    #pragma unroll
    for(int c=0;c<4;c++){
      int cb = wave*4 + c;
      int row = cb*4 + lrow4;
      int col = lcol16 ^ (row & 7);
      glds16(Bt + (size_t)(n0+row)*Kd + kb + col*8, &Bs[buf][cb*512]);
    }
  };

  stage(0, 0);
  __syncthreads();
  int cur = 0;
  for(int kb=0; kb<Kd; kb+=128){
    if(kb + 128 < Kd) stage(cur^1, kb+128);   // prefetch stays in flight across compute
    #pragma unroll
    for(int kk=0;kk<4;kk++){
      short8 af[2], bfr[2];
      #pragma unroll
      for(int mi=0;mi<2;mi++){
        int r = wm*32 + mi*16 + lm;
        int p = ((kk<<2)+lq) ^ (r & 7);
        union{ uint4 u; short8 v; } x;
        x.u = *(const uint4*)&As[cur][r*128 + p*8];
        af[mi] = x.v;
      }
      #pragma unroll
      for(int ni=0;ni<2;ni++){
        int r = wn*32 + ni*16 + lm;
        int p = ((kk<<2)+lq) ^ (r & 7);
        union{ uint4 u; short8 v; } x;
        x.u = *(const uint4*)&Bs[cur][r*128 + p*8];
        bfr[ni] = x.v;
      }
      #pragma unroll
      for(int mi=0;mi<2;mi++)
        #pragma unroll
        for(int ni=0;ni<2;ni++)
          acc[mi][ni] = __builtin_amdgcn_mfma_f32_16x16x32_bf16(af[mi], bfr[ni], acc[mi][ni], 0, 0, 0);
    }
    __syncthreads();   // drains vmcnt (prefetch landed) + lgkmcnt
    cur ^= 1;
  }

  #pragma unroll
  for(int ni=0;ni<2;ni++){
    int col = n0 + wn*32 + ni*16 + lm;
    float bs = fbias ? ((const float*)bias)[col] : bf2f(((const u16*)bias)[col]);
    float av = 0.f;
    if(EPI==1) av = fpa ? ((const float*)pa)[col] : bf2f(((const u16*)pa)[col]);
    #pragma unroll
    for(int mi=0;mi<2;mi++){
      int rowb = m0 + wm*32 + mi*16 + lq*4;
      #pragma unroll
      for(int r2=0;r2<4;r2++){
        float v = acc[mi][ni][r2] + bs;
        if(EPI==0){
          v = fmaxf(v, 0.f);
          ((u16*)Cout)[(size_t)(rowb+r2)*Nd + col] = f2bf(v);
        } else {
          v = (v > 0.f) ? v : av*v;
          ((float*)Cout)[(size_t)(rowb+r2)*Nd + col] = v;
        }
      }
    }
  }
}

// ---------------- final: logits = h1 @ w2 + b2, softmax over 2 ----------------
__global__ __launch_bounds__(256) void k_out(
    const float* __restrict__ h1, const void* __restrict__ w2,
    const void* __restrict__ b2, int fw2, int fb2, int fo,
    void* __restrict__ out){
  int t = threadIdx.x; int lane = t & 63; int row = blockIdx.x*4 + (t >> 6);
  const float* hr = h1 + (size_t)row*NH;
  float s0 = 0.f, s1 = 0.f;
  #pragma unroll
  for(int j=0;j<NH/64;j++){
    int i = lane + j*64;
    float h = hr[i];
    float w0 = fw2 ? ((const float*)w2)[i*2+0] : bf2f(((const u16*)w2)[i*2+0]);
    float w1v= fw2 ? ((const float*)w2)[i*2+1] : bf2f(((const u16*)w2)[i*2+1]);
    s0 += h * w0;
    s1 += h * w1v;
  }
  #pragma unroll
  for(int off=32; off>0; off>>=1){
    s0 += __shfl_down(s0, off);
    s1 += __shfl_down(s1, off);
  }
  if(lane==0){
    float bb0 = fb2 ? ((const float*)b2)[0] : bf2f(((const u16*)b2)[0]);
    float bb1 = fb2 ? ((const float*)b2)[1] : bf2f(((const u16*)b2)[1]);
    float l0 = s0 + bb0;
    float l1 = s1 + bb1;
    float m = fmaxf(l0, l1);
    float e0 = expf(l0 - m), e1 = expf(l1 - m);
    float inv = 1.0f / (e0 + e1);
    if(fo){
      ((float*)out)[row*2+0] = e0*inv;
      ((float*)out)[row*2+1] = e1*inv;
    } else {
      ((u16*)out)[row*2+0] = f2bf(e0*inv);
      ((u16*)out)[row*2+1] = f2bf(e1*inv);
    }
  }
}

// ---------------- diagnostic sentinel: ws too small (~3.0 in either dtype) ----------------
__global__ void k_fill_sentinel(u32* __restrict__ out, int nwords){
  int i = blockIdx.x*256 + threadIdx.x;
  if(i < nwords) out[i] = 0x40404040u;
}

extern "C" void kernel_launch(void* const* d_in, const int* in_sizes, int n_in,
                              void* d_out, int out_size, void* d_ws, size_t ws_size,
                              hipStream_t stream) {
  const int* indexes = (const int*)d_in[0];
  const void* feat   = d_in[1];
  const int* labels  = (const int*)d_in[2];
  const int* knn     = (const int*)d_in[3];
  const void* conv_w = d_in[4];
  const void* conv_b = d_in[5];
  const void* w1     = d_in[6];
  const void* b1     = d_in[7];
  const void* pa     = d_in[8];
  const void* w2     = d_in[9];
  const void* b2     = d_in[10];

  // host-side dtype flags from byte sizes (default f32 unless exact bf16 size)
  int ff  = (in_sizes[1]  != (int)((size_t)NPTS*DD*2));
  int fcw = (in_sizes[4]  != (int)((size_t)2*DD*NH*2));
  int fcb = (in_sizes[5]  != NH*2);
  int fw1 = (in_sizes[6]  != (int)((size_t)NH*NH*2));
  int fb1 = (in_sizes[7]  != NH*2);
  int fpa = (in_sizes[8]  != NH*2);
  int fw2 = (in_sizes[9]  != NH*2*2);
  int fb2 = (in_sizes[10] != 2*2);
  int fo  = (out_size     != MM*2*2);

  char* w = (char*)d_ws;
  size_t o = 0;
  auto alloc = [&](size_t bytes) -> void* {
    void* p = w + o; o = (o + bytes + 255) & ~(size_t)255; return p;
  };
  int*   counts  = (int*)  alloc((size_t)NCC*4);
  int*   cursor  = (int*)  alloc((size_t)NCC*4);
  int*   used    = (int*)  alloc((size_t)NCC*4);
  int*   offsets = (int*)  alloc((size_t)NCC*4);
  int*   sorted  = (int*)  alloc((size_t)NPTS*4);
  float* norms   = (float*)alloc((size_t)MM*4);
  float* adj     = (float*)alloc((size_t)BB*64*64*4);
  float* Apart   = (float*)alloc((size_t)4*BB*64*64*4);  // 4 MB partial A
  float* clu     = (float*)alloc((size_t)NCC*DD*4);   // 16 MB; dead before GEMMs
  u16*   xab     = (u16*)  alloc((size_t)MM*K2*2);    // 32 MB
  u16*   cwT     = (u16*)  alloc((size_t)K2*NH*2);    // 4 MB
  u16*   w1T     = (u16*)  alloc((size_t)NH*NH*2);    // 0.5 MB
  u16*   hb      = (u16*)  clu;                       // alias: 4 MB
  float* h1      = (float*)((char*)clu + (size_t)MM*NH*2); // alias: 8 MB

  size_t NEED = o;
  if(ws_size < NEED){
    int nwords = out_size/4;
    k_fill_sentinel<<<(nwords+255)/256, 256, 0, stream>>>((u32*)d_out, nwords);
    return;
  }

  hipMemsetAsync(counts, 0, (size_t)NCC*4*3, stream);   // counts + cursor + used

  k_prep   <<<705, 256, 0, stream>>>(labels, counts, knn, used, conv_w, cwT, fcw, w1, w1T, fw1);
  k_scan   <<<1, 256, 0, stream>>>(counts, offsets);
  k_scatter<<<NPTS/256, 256, 0, stream>>>(labels, offsets, cursor, sorted);
  k_clumean<<<NCC, 256, 0, stream>>>(feat, counts, offsets, sorted, used, ff, clu);
  k_Apart  <<<BB*4, 256, 0, stream>>>(feat, clu, indexes, labels, knn, ff, Apart);
  k_Afinal <<<BB, 256, 0, stream>>>(Apart, labels, knn, adj, norms);
  k_xagg   <<<BB*8, 256, 0, stream>>>(feat, clu, indexes, labels, knn, norms, adj, ff, xab);

  k_gemm<0><<<(MM/64)*(NH/64), 256, 0, stream>>>(xab, cwT, conv_b, nullptr, fcb, 0, (void*)hb, MM, NH, K2);
  k_gemm<1><<<(MM/64)*(NH/64), 256, 0, stream>>>(hb, w1T, b1, pa, fb1, fpa, (void*)h1, MM, NH, NH);

  k_out    <<<MM/4, 256, 0, stream>>>(h1, w2, b2, fw2, fb2, fo, d_out);
}

// Round 6
// 527.089 us; speedup vs baseline: 2.2362x; 1.0130x over previous
//
#include <hip/hip_runtime.h>
#include <hip/hip_bf16.h>

#define BB 64
#define KN 64
#define NPTS 32768
#define DD 2048
#define NCC 2048
#define NH 512
#define MM 4096   /* BB*KN */
#define K2 4096   /* 2*DD  */
#define MCLUB 2112 /* NCC + BB q-rows */

typedef unsigned short u16;
typedef unsigned int u32;
typedef __attribute__((ext_vector_type(8))) short short8;
typedef __attribute__((ext_vector_type(4))) float f32x4;

__device__ __forceinline__ float bf2f(u32 u){
  union { u32 i; float f; } v; v.i = u << 16; return v.f;
}
__device__ __forceinline__ u16 f2bf(float f){
  union { float f; u32 i; } v; v.f = f;
  u32 x = v.i;
  return (u16)((x + 0x7fffu + ((x >> 16) & 1u)) >> 16);
}
__device__ __forceinline__ uint4 pack8(const u16* b){
  uint4 w;
  w.x = (u32)b[0] | ((u32)b[1]<<16);
  w.y = (u32)b[2] | ((u32)b[3]<<16);
  w.z = (u32)b[4] | ((u32)b[5]<<16);
  w.w = (u32)b[6] | ((u32)b[7]<<16);
  return w;
}

// global_load_lds: per-lane global src, wave-uniform LDS base (+lane*16 by HW)
typedef __attribute__((address_space(3))) u32 as3_u32;
typedef const __attribute__((address_space(1))) u32 as1_u32;
__device__ __forceinline__ void glds16(const void* g, void* l){
  __builtin_amdgcn_global_load_lds((as1_u32*)g, (as3_u32*)l, 16, 0, 0);
}

// ---------------- fused prep: label count + used mark + weight transposes ----------------
// [0,128): count labels; [128,640): conv_w -> cwT2 [1024,2048] split-transpose;
// [640,704): w1 -> w1T [512,512]; [704]: mark used clusters.
__global__ __launch_bounds__(256) void k_prep(
    const int* __restrict__ labels, int* __restrict__ counts,
    const int* __restrict__ knn, int* __restrict__ used,
    const void* __restrict__ conv_w, u16* __restrict__ cwT2, int fcw,
    const void* __restrict__ w1, u16* __restrict__ w1T, int fw1){
  __shared__ u16 tile[64][65];
  int bb = blockIdx.x, t = threadIdx.x;
  if(bb < 128){
    atomicAdd(&counts[labels[bb*256 + t]], 1);
    return;
  }
  if(bb == 704){
    #pragma unroll
    for(int i=0;i<16;i++) used[labels[knn[i*256 + t]]] = 1;
    return;
  }
  if(bb < 640){
    int tb = bb - 128;                 // conv_w [4096,512]: 64x8 tiles
    int k0 = (tb >> 3) << 6;
    int n0 = (tb & 7) << 6;
    if(fcw){
      const float* s = (const float*)conv_w;
      #pragma unroll
      for(int ph=0; ph<16; ph++){
        int idx = ph*256 + t; int r = idx >> 6, c = idx & 63;
        tile[r][c] = f2bf(s[(size_t)(k0+r)*NH + n0 + c]);
      }
    } else {
      const u16* s = (const u16*)conv_w;
      #pragma unroll
      for(int ph=0; ph<16; ph++){
        int idx = ph*256 + t; int r = idx >> 6, c = idx & 63;
        tile[r][c] = s[(size_t)(k0+r)*NH + n0 + c];
      }
    }
    __syncthreads();
    // dst row j = n0+r + (k0>=2048 ? 512 : 0)  (Wx rows 0..511, Wa rows 512..1023)
    // dst col k2 = (k0&2047) + c
    int drow = n0 + (k0 >= 2048 ? 512 : 0);
    int dcol = k0 & 2047;
    #pragma unroll
    for(int ph=0; ph<16; ph++){
      int idx = ph*256 + t; int r = idx >> 6, c = idx & 63;
      cwT2[(size_t)(drow+r)*2048 + dcol + c] = tile[c][r];
    }
  } else {
    int tb = bb - 640;                 // w1 [512,512]: 8x8 tiles
    int k0 = (tb >> 3) << 6;
    int n0 = (tb & 7) << 6;
    if(fw1){
      const float* s = (const float*)w1;
      #pragma unroll
      for(int ph=0; ph<16; ph++){
        int idx = ph*256 + t; int r = idx >> 6, c = idx & 63;
        tile[r][c] = f2bf(s[(size_t)(k0+r)*NH + n0 + c]);
      }
    } else {
      const u16* s = (const u16*)w1;
      #pragma unroll
      for(int ph=0; ph<16; ph++){
        int idx = ph*256 + t; int r = idx >> 6, c = idx & 63;
        tile[r][c] = s[(size_t)(k0+r)*NH + n0 + c];
      }
    }
    __syncthreads();
    #pragma unroll
    for(int ph=0; ph<16; ph++){
      int idx = ph*256 + t; int r = idx >> 6, c = idx & 63;
      w1T[(size_t)(n0+r)*NH + k0 + c] = tile[c][r];
    }
  }
}

__global__ void k_scan(const int* __restrict__ counts, int* __restrict__ offsets){
  __shared__ int sb[256];
  int t = threadIdx.x;
  int c[8]; int s = 0;
  #pragma unroll
  for(int i=0;i<8;i++){ c[i] = counts[t*8+i]; s += c[i]; }
  sb[t] = s; __syncthreads();
  int v = s;
  for(int off=1; off<256; off<<=1){
    int u = (t>=off) ? sb[t-off] : 0;
    __syncthreads();
    v += u; sb[t] = v;
    __syncthreads();
  }
  int run = v - s;
  #pragma unroll
  for(int i=0;i<8;i++){ offsets[t*8+i] = run; run += c[i]; }
}

__global__ void k_scatter(const int* __restrict__ labels, const int* __restrict__ offsets,
                          int* __restrict__ cursor, int* __restrict__ sorted){
  int n = blockIdx.x*256 + threadIdx.x;
  int c = labels[n];
  int p = atomicAdd(&cursor[c], 1);
  sorted[offsets[c] + p] = n;
}

// ---------------- q rows -> club rows [2048, 2112) in bf16 ----------------
__global__ __launch_bounds__(256) void k_qcopy(
    const void* __restrict__ feat, const int* __restrict__ indexes,
    int ff, u16* __restrict__ club){
  int b = blockIdx.x, t = threadIdx.x;
  int qidx = indexes[b];
  u16* o = club + (size_t)(NCC + b)*DD + t*8;
  if(ff){
    const float* p = (const float*)feat + (size_t)qidx*DD + t*8;
    float4 a = *(const float4*)p, c = *(const float4*)(p+4);
    u16 ob[8] = {f2bf(a.x),f2bf(a.y),f2bf(a.z),f2bf(a.w),
                 f2bf(c.x),f2bf(c.y),f2bf(c.z),f2bf(c.w)};
    *(uint4*)o = pack8(ob);
  } else {
    uint4 v = *(const uint4*)((const u16*)feat + (size_t)qidx*DD + t*8);
    *(uint4*)o = v;
  }
}

// ---------------- cluster means: f32 clu + bf16 club; zero unused club rows ----------------
__global__ __launch_bounds__(256) void k_clumean(
    const void* __restrict__ feat, const int* __restrict__ counts,
    const int* __restrict__ offsets, const int* __restrict__ sorted,
    const int* __restrict__ used, int isf32,
    float* __restrict__ clu, u16* __restrict__ club){
  int c = blockIdx.x, t = threadIdx.x;
  if(!used[c]){
    // unused: zero club row so workspace poison can't enter the PR GEMM
    *(uint4*)(club + (size_t)c*DD + t*8) = make_uint4(0,0,0,0);
    return;
  }
  __shared__ int ridx[64];
  int cnt = counts[c], start = offsets[c];
  float acc[8] = {0,0,0,0,0,0,0,0};
  for(int base=0; base<cnt; base+=64){
    int take = min(64, cnt-base);
    __syncthreads();
    if(t < take) ridx[t] = sorted[start+base+t];
    __syncthreads();
    if(isf32){
      const float* ff = (const float*)feat;
      int r = 0;
      for(; r+4<=take; r+=4){
        const float* p0 = ff + (size_t)ridx[r]*DD + t*8;
        const float* p1 = ff + (size_t)ridx[r+1]*DD + t*8;
        const float* p2 = ff + (size_t)ridx[r+2]*DD + t*8;
        const float* p3 = ff + (size_t)ridx[r+3]*DD + t*8;
        float4 a0=*(const float4*)p0, b0=*(const float4*)(p0+4);
        float4 a1=*(const float4*)p1, b1=*(const float4*)(p1+4);
        float4 a2=*(const float4*)p2, b2=*(const float4*)(p2+4);
        float4 a3=*(const float4*)p3, b3=*(const float4*)(p3+4);
        acc[0]+=a0.x+a1.x+a2.x+a3.x; acc[1]+=a0.y+a1.y+a2.y+a3.y;
        acc[2]+=a0.z+a1.z+a2.z+a3.z; acc[3]+=a0.w+a1.w+a2.w+a3.w;
        acc[4]+=b0.x+b1.x+b2.x+b3.x; acc[5]+=b0.y+b1.y+b2.y+b3.y;
        acc[6]+=b0.z+b1.z+b2.z+b3.z; acc[7]+=b0.w+b1.w+b2.w+b3.w;
      }
      for(; r<take; r++){
        const float* p0 = ff + (size_t)ridx[r]*DD + t*8;
        float4 a0=*(const float4*)p0, b0=*(const float4*)(p0+4);
        acc[0]+=a0.x; acc[1]+=a0.y; acc[2]+=a0.z; acc[3]+=a0.w;
        acc[4]+=b0.x; acc[5]+=b0.y; acc[6]+=b0.z; acc[7]+=b0.w;
      }
    } else {
      const u16* fb = (const u16*)feat;
      for(int r=0; r<take; r++){
        const u16* p0 = fb + (size_t)ridx[r]*DD + t*8;
        uint4 v0 = *(const uint4*)p0;
        acc[0]+=bf2f(v0.x&0xffffu); acc[1]+=bf2f(v0.x>>16);
        acc[2]+=bf2f(v0.y&0xffffu); acc[3]+=bf2f(v0.y>>16);
        acc[4]+=bf2f(v0.z&0xffffu); acc[5]+=bf2f(v0.z>>16);
        acc[6]+=bf2f(v0.w&0xffffu); acc[7]+=bf2f(v0.w>>16);
      }
    }
  }
  float div = fmaxf((float)cnt, 1.0f);
  float m[8];
  #pragma unroll
  for(int i=0;i<8;i++) m[i] = acc[i] / div;
  float* o = clu + (size_t)c*DD + t*8;
  *(float4*)o     = make_float4(m[0],m[1],m[2],m[3]);
  *(float4*)(o+4) = make_float4(m[4],m[5],m[6],m[7]);
  u16 ob[8];
  #pragma unroll
  for(int i=0;i<8;i++) ob[i] = f2bf(m[i]);
  *(uint4*)(club + (size_t)c*DD + t*8) = pack8(ob);
}

// ---------------- partial A: block (b, dgroup g) accumulates 512 dims (f32 clu) ----------------
__global__ __launch_bounds__(256) void k_Apart(
    const void* __restrict__ feat, const float* __restrict__ clu,
    const int* __restrict__ indexes, const int* __restrict__ labels,
    const int* __restrict__ knn, int isf32, float* __restrict__ Apart){
  int b = blockIdx.x >> 2, g = blockIdx.x & 3;
  int t = threadIdx.x;
  __shared__ float cfT[64][68];
  __shared__ int sl[64];
  if(t < 64) sl[t] = labels[knn[b*64 + t]];
  int qidx = indexes[b];
  __syncthreads();
  int i0 = (t & 15)*4, j0 = (t >> 4)*4;
  float acc[4][4];
  #pragma unroll
  for(int x=0;x<4;x++)
    #pragma unroll
    for(int c2=0;c2<4;c2++) acc[x][c2] = 0.f;
  for(int ch=g*8; ch<g*8+8; ch++){
    int dbase = ch*64;
    #pragma unroll
    for(int ps=0; ps<16; ps++){
      int idx = ps*256 + t;
      int k = idx >> 6, dd = idx & 63;
      float v;
      if(k == 0){
        size_t fi = (size_t)qidx*DD + dbase + dd;
        v = isf32 ? ((const float*)feat)[fi] : bf2f(((const u16*)feat)[fi]);
      } else {
        v = clu[(size_t)sl[k]*DD + dbase + dd];
      }
      cfT[dd][k] = v;
    }
    __syncthreads();
    #pragma unroll 4
    for(int dd=0; dd<64; dd++){
      float4 av = *(const float4*)&cfT[dd][i0];
      float4 bv = *(const float4*)&cfT[dd][j0];
      float aa[4] = {av.x, av.y, av.z, av.w};
      float bbv[4] = {bv.x, bv.y, bv.z, bv.w};
      #pragma unroll
      for(int ii=0;ii<4;ii++)
        #pragma unroll
        for(int jj=0;jj<4;jj++)
          acc[ii][jj] += aa[ii]*bbv[jj];
    }
    __syncthreads();
  }
  float* op = Apart + ((size_t)(g*64 + b))*4096;
  #pragma unroll
  for(int ii=0;ii<4;ii++)
    *(float4*)&op[(i0+ii)*64 + j0] = make_float4(acc[ii][0], acc[ii][1], acc[ii][2], acc[ii][3]);
}

// ---------------- final A: sum partials, keep mask, top-5, norms, adj ----------------
__global__ __launch_bounds__(256) void k_Afinal(
    const float* __restrict__ Apart, const int* __restrict__ labels,
    const int* __restrict__ knn,
    float* __restrict__ adj, float* __restrict__ norms){
  int b = blockIdx.x, t = threadIdx.x;
  __shared__ float A[64][65];
  __shared__ unsigned long long mb[64];
  __shared__ int sl[64];
  __shared__ int sk[64];
  if(t < 64) sl[t] = labels[knn[b*64 + t]];
  const float* P = Apart + (size_t)b*4096;
  const size_t gs = (size_t)64*4096;
  #pragma unroll
  for(int ps=0; ps<16; ps++){
    int idx = ps*256 + t;
    float s = P[idx] + P[idx+gs] + P[idx+2*gs] + P[idx+3*gs];
    A[idx>>6][idx&63] = s * 0.2f;
  }
  __syncthreads();
  if(t < 64){
    int dup = 0;
    for(int j=0;j<t;j++) dup |= (sl[j]==sl[t]);
    sk[t] = dup ? 0 : 1;
    unsigned long long chosen = 0;
    const float* row = A[t];
    #pragma unroll
    for(int p=0;p<5;p++){
      float best = -INFINITY; int bi = 0;
      for(int j=0;j<64;j++){
        bool taken = (chosen >> j) & 1ull;
        float v = row[j];
        if(!taken && v > best){ best = v; bi = j; }
      }
      chosen |= (1ull << bi);
    }
    mb[t] = chosen;
    norms[b*64+t] = sqrtf(fmaxf(A[t][t]*5.0f, 0.0f));
  }
  __syncthreads();
  float* O = adj + (size_t)b*4096;
  #pragma unroll
  for(int ps=0; ps<16; ps++){
    int idx = ps*256 + t;
    int i = idx >> 6, j = idx & 63;
    bool on = ((mb[i]>>j)&1ull) && ((mb[j]>>i)&1ull) && sk[i] && sk[j];
    O[idx] = on ? A[i][j] : 0.0f;
  }
}

// ---------------- h combine: h = relu(xWx + A@(xWa) + conv_b) from PR gathers ----------------
// block (b, colgroup of 128). xWx/xWa[k] = invk*PR[sl[k]] - inv0*PR[q-row]; row 0 = 0.
__global__ __launch_bounds__(256) void k_hcomb(
    const float* __restrict__ PR, const float* __restrict__ adj,
    const float* __restrict__ norms, const int* __restrict__ labels,
    const int* __restrict__ knn, const void* __restrict__ conv_b, int fcb,
    u16* __restrict__ hb){
  int b = blockIdx.x >> 2, cg = blockIdx.x & 3;
  int t = threadIdx.x;
  __shared__ float adjs[64][65];
  __shared__ float xwa[64][128];
  __shared__ float cqx[128], cqa[128], bias[128];
  __shared__ float nzv[64][8];
  __shared__ u16   nzj[64][8];
  __shared__ int   nzc[64];
  __shared__ int   sl[64];
  __shared__ float sn[64];
  int j0 = cg*128;
  const float* Ab = adj + (size_t)b*4096;
  #pragma unroll
  for(int ps=0; ps<16; ps++){
    int idx = ps*256 + t;
    adjs[idx>>6][idx&63] = Ab[idx];
  }
  if(t < 64){
    sl[t] = labels[knn[b*64 + t]];
    sn[t] = 1.0f / fmaxf(norms[b*64 + t], 1e-30f);
  }
  if(t >= 64 && t < 192){
    int c = t - 64;
    const float* qr = PR + (size_t)(NCC + b)*1024;
    cqx[c] = qr[j0 + c];
    cqa[c] = qr[512 + j0 + c];
    bias[c] = fcb ? ((const float*)conv_b)[j0 + c] : bf2f(((const u16*)conv_b)[j0 + c]);
  }
  __syncthreads();
  if(t < 64){
    int c = 0;
    for(int j=0;j<64;j++){
      float v = adjs[t][j];
      if(v != 0.0f && c < 8){ nzv[t][c] = v; nzj[t][c] = (u16)j; c++; }
    }
    nzc[t] = c;
  }
  float inv0 = sn[0];
  // phase 1: xwa into LDS (row 0 is exactly 0: x[0]=0)
  for(int idx=t; idx<8192; idx+=256){
    int k = idx >> 7, c = idx & 127;
    float v = 0.f;
    if(k > 0) v = sn[k]*PR[(size_t)sl[k]*1024 + 512 + j0 + c] - inv0*cqa[c];
    xwa[k][c] = v;
  }
  __syncthreads();
  // phase 2: h = relu(xwx + sparse-agg + bias)
  for(int idx=t; idx<8192; idx+=256){
    int k = idx >> 7, c = idx & 127;
    float xwx = (k > 0) ? sn[k]*PR[(size_t)sl[k]*1024 + j0 + c] - inv0*cqx[c] : 0.f;
    float g = 0.f;
    int cc = nzc[k];
    for(int p=0;p<cc;p++) g += nzv[k][p]*xwa[nzj[k][p]][c];
    float h = fmaxf(xwx + g + bias[c], 0.f);
    hb[(size_t)(b*64 + k)*NH + j0 + c] = f2bf(h);
  }
}

// ---------------- bf16 MFMA GEMM: BM=BN=64, BK=128, EPI: 1=PReLU->f32, 2=raw f32 ----------------
template<int EPI>
__global__ __launch_bounds__(256, 2) void k_gemm(
    const u16* __restrict__ Am, const u16* __restrict__ Bt,
    const void* __restrict__ bias, const void* __restrict__ pa,
    int fbias, int fpa,
    void* __restrict__ Cout, int Md, int Nd, int Kd)
{
  __shared__ u16 As[2][64*128];
  __shared__ u16 Bs[2][64*128];
  int t = threadIdx.x;
  int nblk = gridDim.x;
  int bid = (blockIdx.x & 7)*(nblk >> 3) + (blockIdx.x >> 3);  // XCD chunking (nblk%8==0)
  int nb = Nd >> 6;
  int m0 = (bid / nb) << 6;
  int n0 = (bid % nb) << 6;
  int wave = t >> 6, lane = t & 63;
  int wm = wave >> 1, wn = wave & 1;
  int lm = lane & 15, lq = lane >> 4;
  int lrow4 = lane >> 4, lcol16 = lane & 15;

  f32x4 acc[2][2];
  #pragma unroll
  for(int i=0;i<2;i++)
    #pragma unroll
    for(int j=0;j<2;j++) acc[i][j] = (f32x4){0.f,0.f,0.f,0.f};

  auto stage = [&](int buf, int kb){
    #pragma unroll
    for(int c=0;c<4;c++){
      int cb = wave*4 + c;
      int row = cb*4 + lrow4;
      int col = lcol16 ^ (row & 7);
      glds16(Am + (size_t)(m0+row)*Kd + kb + col*8, &As[buf][cb*512]);
    }
    #pragma unroll
    for(int c=0;c<4;c++){
      int cb = wave*4 + c;
      int row = cb*4 + lrow4;
      int col = lcol16 ^ (row & 7);
      glds16(Bt + (size_t)(n0+row)*Kd + kb + col*8, &Bs[buf][cb*512]);
    }
  };

  stage(0, 0);
  __syncthreads();
  int cur = 0;
  for(int kb=0; kb<Kd; kb+=128){
    if(kb + 128 < Kd) stage(cur^1, kb+128);
    #pragma unroll
    for(int kk=0;kk<4;kk++){
      short8 af[2], bfr[2];
      #pragma unroll
      for(int mi=0;mi<2;mi++){
        int r = wm*32 + mi*16 + lm;
        int p = ((kk<<2)+lq) ^ (r & 7);
        union{ uint4 u; short8 v; } x;
        x.u = *(const uint4*)&As[cur][r*128 + p*8];
        af[mi] = x.v;
      }
      #pragma unroll
      for(int ni=0;ni<2;ni++){
        int r = wn*32 + ni*16 + lm;
        int p = ((kk<<2)+lq) ^ (r & 7);
        union{ uint4 u; short8 v; } x;
        x.u = *(const uint4*)&Bs[cur][r*128 + p*8];
        bfr[ni] = x.v;
      }
      #pragma unroll
      for(int mi=0;mi<2;mi++)
        #pragma unroll
        for(int ni=0;ni<2;ni++)
          acc[mi][ni] = __builtin_amdgcn_mfma_f32_16x16x32_bf16(af[mi], bfr[ni], acc[mi][ni], 0, 0, 0);
    }
    __syncthreads();
    cur ^= 1;
  }

  #pragma unroll
  for(int ni=0;ni<2;ni++){
    int col = n0 + wn*32 + ni*16 + lm;
    float bs = 0.f, av = 0.f;
    if(EPI != 2) bs = fbias ? ((const float*)bias)[col] : bf2f(((const u16*)bias)[col]);
    if(EPI == 1) av = fpa ? ((const float*)pa)[col] : bf2f(((const u16*)pa)[col]);
    #pragma unroll
    for(int mi=0;mi<2;mi++){
      int rowb = m0 + wm*32 + mi*16 + lq*4;
      #pragma unroll
      for(int r2=0;r2<4;r2++){
        float v = acc[mi][ni][r2] + bs;
        if(EPI==2){
          ((float*)Cout)[(size_t)(rowb+r2)*Nd + col] = v;
        } else { // EPI==1: PReLU
          v = (v > 0.f) ? v : av*v;
          ((float*)Cout)[(size_t)(rowb+r2)*Nd + col] = v;
        }
      }
    }
  }
}

// ---------------- final: logits = h1 @ w2 + b2, softmax over 2 ----------------
__global__ __launch_bounds__(256) void k_out(
    const float* __restrict__ h1, const void* __restrict__ w2,
    const void* __restrict__ b2, int fw2, int fb2, int fo,
    void* __restrict__ out){
  int t = threadIdx.x; int lane = t & 63; int row = blockIdx.x*4 + (t >> 6);
  const float* hr = h1 + (size_t)row*NH;
  float s0 = 0.f, s1 = 0.f;
  #pragma unroll
  for(int j=0;j<NH/64;j++){
    int i = lane + j*64;
    float h = hr[i];
    float w0 = fw2 ? ((const float*)w2)[i*2+0] : bf2f(((const u16*)w2)[i*2+0]);
    float w1v= fw2 ? ((const float*)w2)[i*2+1] : bf2f(((const u16*)w2)[i*2+1]);
    s0 += h * w0;
    s1 += h * w1v;
  }
  #pragma unroll
  for(int off=32; off>0; off>>=1){
    s0 += __shfl_down(s0, off);
    s1 += __shfl_down(s1, off);
  }
  if(lane==0){
    float bb0 = fb2 ? ((const float*)b2)[0] : bf2f(((const u16*)b2)[0]);
    float bb1 = fb2 ? ((const float*)b2)[1] : bf2f(((const u16*)b2)[1]);
    float l0 = s0 + bb0;
    float l1 = s1 + bb1;
    float m = fmaxf(l0, l1);
    float e0 = expf(l0 - m), e1 = expf(l1 - m);
    float inv = 1.0f / (e0 + e1);
    if(fo){
      ((float*)out)[row*2+0] = e0*inv;
      ((float*)out)[row*2+1] = e1*inv;
    } else {
      ((u16*)out)[row*2+0] = f2bf(e0*inv);
      ((u16*)out)[row*2+1] = f2bf(e1*inv);
    }
  }
}

// ---------------- diagnostic sentinel: ws too small ----------------
__global__ void k_fill_sentinel(u32* __restrict__ out, int nwords){
  int i = blockIdx.x*256 + threadIdx.x;
  if(i < nwords) out[i] = 0x40404040u;
}

extern "C" void kernel_launch(void* const* d_in, const int* in_sizes, int n_in,
                              void* d_out, int out_size, void* d_ws, size_t ws_size,
                              hipStream_t stream) {
  const int* indexes = (const int*)d_in[0];
  const void* feat   = d_in[1];
  const int* labels  = (const int*)d_in[2];
  const int* knn     = (const int*)d_in[3];
  const void* conv_w = d_in[4];
  const void* conv_b = d_in[5];
  const void* w1     = d_in[6];
  const void* b1     = d_in[7];
  const void* pa     = d_in[8];
  const void* w2     = d_in[9];
  const void* b2     = d_in[10];

  // host-side dtype flags from byte sizes (default f32 unless exact bf16 size)
  int ff  = (in_sizes[1]  != (int)((size_t)NPTS*DD*2));
  int fcw = (in_sizes[4]  != (int)((size_t)2*DD*NH*2));
  int fcb = (in_sizes[5]  != NH*2);
  int fw1 = (in_sizes[6]  != (int)((size_t)NH*NH*2));
  int fb1 = (in_sizes[7]  != NH*2);
  int fpa = (in_sizes[8]  != NH*2);
  int fw2 = (in_sizes[9]  != NH*2*2);
  int fb2 = (in_sizes[10] != 2*2);
  int fo  = (out_size     != MM*2*2);

  char* w = (char*)d_ws;
  size_t o = 0;
  auto alloc = [&](size_t bytes) -> void* {
    void* p = w + o; o = (o + bytes + 255) & ~(size_t)255; return p;
  };
  int*   counts  = (int*)  alloc((size_t)NCC*4);
  int*   cursor  = (int*)  alloc((size_t)NCC*4);
  int*   used    = (int*)  alloc((size_t)NCC*4);
  int*   offsets = (int*)  alloc((size_t)NCC*4);
  int*   sorted  = (int*)  alloc((size_t)NPTS*4);
  float* norms   = (float*)alloc((size_t)MM*4);
  float* adj     = (float*)alloc((size_t)BB*64*64*4);
  float* Apart   = (float*)alloc((size_t)4*BB*64*64*4);   // 4 MB
  float* clu     = (float*)alloc((size_t)NCC*DD*4);       // 16 MB (f32, for Apart)
  u16*   club    = (u16*)  alloc((size_t)MCLUB*DD*2);     // 8.6 MB bf16 [clu ; q-rows]
  float* PR      = (float*)alloc((size_t)MCLUB*1024*4);   // 8.6 MB [clu;q] @ [Wx|Wa]
  u16*   cwT2    = (u16*)  alloc((size_t)1024*2048*2);    // 4 MB
  u16*   w1T     = (u16*)  alloc((size_t)NH*NH*2);        // 0.5 MB
  u16*   hb      = (u16*)  clu;                           // alias: 4 MB (clu dead after Apart)
  float* h1      = (float*)((char*)clu + (size_t)MM*NH*2);// alias: 8 MB

  size_t NEED = o;
  if(ws_size < NEED){
    int nwords = out_size/4;
    k_fill_sentinel<<<(nwords+255)/256, 256, 0, stream>>>((u32*)d_out, nwords);
    return;
  }

  hipMemsetAsync(counts, 0, (size_t)NCC*4*3, stream);   // counts + cursor + used

  k_prep   <<<705, 256, 0, stream>>>(labels, counts, knn, used, conv_w, cwT2, fcw, w1, w1T, fw1);
  k_scan   <<<1, 256, 0, stream>>>(counts, offsets);
  k_scatter<<<NPTS/256, 256, 0, stream>>>(labels, offsets, cursor, sorted);
  k_qcopy  <<<BB, 256, 0, stream>>>(feat, indexes, ff, club);
  k_clumean<<<NCC, 256, 0, stream>>>(feat, counts, offsets, sorted, used, ff, clu, club);

  // PR = [clu ; q] @ [Wx|Wa]: M=2112, N=1024, K=2048 (raw f32 out)
  k_gemm<2><<<(MCLUB/64)*(1024/64), 256, 0, stream>>>(club, cwT2, nullptr, nullptr, 0, 0,
                                                      (void*)PR, MCLUB, 1024, 2048);

  k_Apart  <<<BB*4, 256, 0, stream>>>(feat, clu, indexes, labels, knn, ff, Apart);
  k_Afinal <<<BB, 256, 0, stream>>>(Apart, labels, knn, adj, norms);
  k_hcomb  <<<BB*4, 256, 0, stream>>>(PR, adj, norms, labels, knn, conv_b, fcb, hb);

  k_gemm<1><<<(MM/64)*(NH/64), 256, 0, stream>>>(hb, w1T, b1, pa, fb1, fpa, (void*)h1, MM, NH, NH);

  k_out    <<<MM/4, 256, 0, stream>>>(h1, w2, b2, fw2, fb2, fo, d_out);
}